// Round 3
// baseline (494.188 us; speedup 1.0000x reference)
//
#include <hip/hip_runtime.h>
#include <hip/hip_fp16.h>

#define N_GRAPHS_C 256
#define CHUNK_LOG 13
#define CHUNK (1 << CHUNK_LOG)   // 8192 atoms per bucket
#define MAXB 32
#define NSLICE 20                // passB slices per bucket (64 KB LDS -> 2 blocks/CU)
#define NSLICE_FB 10
#define TPA 256
#define TPBB 1024

// ---------------- shared per-edge math ----------------
// Units: Angstrom, electron charge, eV (avoids fp32 denormals from the
// reference's SI-unit charges; algebraically identical).
__device__ __forceinline__ void edge_math(
    float dx, float dy, float dz, float qr, float qc, float gA,
    float& fx, float& fy, float& fz, float& ecoul)
{
    const float KEV = (float)(8987551792.3 * 1.602176634e-9); // 14.3996 eV*A/e^2
    float r2 = dx * dx + dy * dy + dz * dz;
    float inv_r = rsqrtf(r2);
    float rA = r2 * inv_r;

    float pref = KEV * qr * qc * inv_r;

    float damp = 1.0f;
    if (rA < 2.2f)
        damp = __expf(-18.7f * (2.2f - rA) * (1.0f / 2.2f));

    float grij = gA * rA;
    float expm2 = __expf(-grij * grij);
    float t = 1.0f / (1.0f + 0.3275911f * grij);
    float erfc = t * (0.254829592f +
                 t * (-0.284496736f +
                 t * (1.421413741f +
                 t * (-1.453152027f +
                 t * 1.061405429f)))) * expm2;

    ecoul = pref * (0.5f * damp + (erfc - 1.0f));
    float S = damp + erfc + 2.0f * grij * expm2 - 1.0f;
    float fs = pref * S * (inv_r * inv_r);
    fx = dx * fs; fy = dy * fs; fz = dz * fs;
}

__device__ __forceinline__ uint2 pack_rec(float fx, float fy, float fz, unsigned lid)
{
    uint2 u;
    u.x = __builtin_bit_cast(unsigned, __floats2half2_rn(fx, fy));
    u.y = (__builtin_bit_cast(unsigned, __floats2half2_rn(fz, 0.0f)) & 0xFFFFu) |
          (lid << 16);
    return u;
}

// passB helpers: DS chain for one uint4 (2 records) / one uint2 (1 record).
// asm volatile without "memory" clobber: DS ops stay ordered among themselves
// but record loads are free to hoist ahead of the DS chain.
__device__ __forceinline__ void ds_rec2(unsigned lds_base, uint4 v)
{
    unsigned idxA = v.y >> 16;
    unsigned idxB = v.w >> 16;
    asm volatile("ds_pk_add_f16 %0, %1"
                 :: "v"(lds_base + 4u * idxA), "v"(v.x));
    asm volatile("ds_pk_add_f16 %0, %1"
                 :: "v"(lds_base + 4u * (CHUNK + idxA)), "v"(v.y & 0xFFFFu));
    asm volatile("ds_pk_add_f16 %0, %1"
                 :: "v"(lds_base + 4u * idxB), "v"(v.z));
    asm volatile("ds_pk_add_f16 %0, %1"
                 :: "v"(lds_base + 4u * (CHUNK + idxB)), "v"(v.w & 0xFFFFu));
}
__device__ __forceinline__ void ds_rec1(unsigned lds_base, uint2 t)
{
    unsigned idx = t.y >> 16;
    asm volatile("ds_pk_add_f16 %0, %1"
                 :: "v"(lds_base + 4u * idx), "v"(t.x));
    asm volatile("ds_pk_add_f16 %0, %1"
                 :: "v"(lds_base + 4u * (CHUNK + idx)), "v"(t.y & 0xFFFFu));
}

// prep: fuse q[] and batch[] into one 8 B table so passA does 2 scattered
// gathers per edge instead of 3. Also zeroes ovf[] (replaces a memset launch).
__global__ __launch_bounds__(256) void prep_qg(
    const float* __restrict__ q, const int* __restrict__ batch,
    float2* __restrict__ qg, float* __restrict__ ovf, int n_atoms)
{
    int i = blockIdx.x * 256 + threadIdx.x;
    if (i < n_atoms) {
        qg[i] = make_float2(q[i], __int_as_float(batch[i]));
        ovf[3 * i + 0] = 0.f;
        ovf[3 * i + 1] = 0.f;
        ovf[3 * i + 2] = 0.f;
    }
}

// ================= fast path =================
// passA: dense single sweep. Per edge: 2 scattered 8 B gathers (qg[r], qg[c]),
// ~50 VALU of math, 1 LDS energy atomic, 2 LDS rank atomics, 2 scattered 8 B
// record stores. 2-deep software pipeline on the gathers. Overflow -> ovf[].
__global__ __launch_bounds__(TPA) void passA(
    const float* __restrict__ dij, const float2* __restrict__ qg,
    const float* __restrict__ g_ewald,
    const int* __restrict__ row, const int* __restrict__ col,
    uint2* __restrict__ records, int cap,
    unsigned* __restrict__ cnt_table,
    float* __restrict__ e_part,
    float* __restrict__ ovf,
    int n_edges, int nb, int tile_g)
{
    __shared__ unsigned cnt[MAXB];
    __shared__ float e_graph[4 * N_GRAPHS_C];   // per-wave replicas

    int tid = threadIdx.x;
    if (tid < MAXB) cnt[tid] = 0u;
    for (int i = tid; i < 4 * N_GRAPHS_C; i += TPA) e_graph[i] = 0.f;
    __syncthreads();

    float* e_my = &e_graph[(tid >> 6) * N_GRAPHS_C];

    int n4 = n_edges >> 2;
    int g0 = blockIdx.x * tile_g;
    int g1 = min(g0 + tile_g, n4);

    const int4* row4 = (const int4*)row;
    const int4* col4 = (const int4*)col;
    const float4* dij4 = (const float4*)dij;

    const float gA = g_ewald[0] * 1e-10f;    // 1/m -> 1/Angstrom
    size_t blk_base = (size_t)blockIdx.x * nb * cap;

    int g = g0 + tid;
    int4 r_cur = make_int4(0, 0, 0, 0), c_cur = make_int4(0, 0, 0, 0);
    int4 r_nxt = make_int4(0, 0, 0, 0), c_nxt = make_int4(0, 0, 0, 0);
    float2 vr_cur[4], vc_cur[4];

    if (g < g1) {
        r_cur = row4[g]; c_cur = col4[g];
        vr_cur[0] = qg[r_cur.x]; vc_cur[0] = qg[c_cur.x];
        vr_cur[1] = qg[r_cur.y]; vc_cur[1] = qg[c_cur.y];
        vr_cur[2] = qg[r_cur.z]; vc_cur[2] = qg[c_cur.z];
        vr_cur[3] = qg[r_cur.w]; vc_cur[3] = qg[c_cur.w];
    }
    if (g + TPA < g1) { r_nxt = row4[g + TPA]; c_nxt = col4[g + TPA]; }

    while (g < g1) {
        int gn = g + TPA;

        // issue NEXT group's gathers now (indices prefetched last iteration;
        // zero-init indices make these qg[0] loads when past the end: harmless)
        float2 vr_n[4], vc_n[4];
        vr_n[0] = qg[r_nxt.x]; vc_n[0] = qg[c_nxt.x];
        vr_n[1] = qg[r_nxt.y]; vc_n[1] = qg[c_nxt.y];
        vr_n[2] = qg[r_nxt.z]; vc_n[2] = qg[c_nxt.z];
        vr_n[3] = qg[r_nxt.w]; vc_n[3] = qg[c_nxt.w];

        // prefetch indices two groups ahead (bounds-guarded)
        int4 r_n2 = make_int4(0, 0, 0, 0), c_n2 = make_int4(0, 0, 0, 0);
        if (gn + TPA < g1) { r_n2 = row4[gn + TPA]; c_n2 = col4[gn + TPA]; }

        float4 d0 = dij4[3 * g + 0];
        float4 d1 = dij4[3 * g + 1];
        float4 d2 = dij4[3 * g + 2];
        float ex[4] = {d0.x, d0.w, d1.z, d2.y};
        float ey[4] = {d0.y, d1.x, d1.w, d2.z};
        float ez[4] = {d0.z, d1.y, d2.x, d2.w};
        int rr[4] = {r_cur.x, r_cur.y, r_cur.z, r_cur.w};
        int cc[4] = {c_cur.x, c_cur.y, c_cur.z, c_cur.w};

        #pragma unroll
        for (int j = 0; j < 4; ++j) {
            int r = rr[j], c = cc[j];
            float fx, fy, fz, ec;
            edge_math(ex[j], ey[j], ez[j], vr_cur[j].x, vc_cur[j].x, gA,
                      fx, fy, fz, ec);

            atomicAdd(&e_my[__float_as_int(vr_cur[j].y)], ec);

            int br = r >> CHUNK_LOG, bc = c >> CHUNK_LOG;
            unsigned pr = atomicAdd(&cnt[br], 1u);
            unsigned pc = atomicAdd(&cnt[bc], 1u);
            if (pr < (unsigned)cap)
                records[blk_base + (size_t)br * cap + pr] =
                    pack_rec(fx, fy, fz, (unsigned)(r & (CHUNK - 1)));
            else {
                atomicAdd(&ovf[3 * r + 0], fx);
                atomicAdd(&ovf[3 * r + 1], fy);
                atomicAdd(&ovf[3 * r + 2], fz);
            }
            if (pc < (unsigned)cap)
                records[blk_base + (size_t)bc * cap + pc] =
                    pack_rec(-fx, -fy, -fz, (unsigned)(c & (CHUNK - 1)));
            else {
                atomicAdd(&ovf[3 * c + 0], -fx);
                atomicAdd(&ovf[3 * c + 1], -fy);
                atomicAdd(&ovf[3 * c + 2], -fz);
            }
        }

        g = gn;
        r_cur = r_nxt; c_cur = c_nxt;
        r_nxt = r_n2;  c_nxt = c_n2;
        #pragma unroll
        for (int j = 0; j < 4; ++j) { vr_cur[j] = vr_n[j]; vc_cur[j] = vc_n[j]; }
    }
    __syncthreads();

    if (tid < nb) cnt_table[(size_t)blockIdx.x * nb + tid] = min(cnt[tid], (unsigned)cap);
    for (int g2 = tid; g2 < N_GRAPHS_C; g2 += TPA)
        e_part[(size_t)blockIdx.x * N_GRAPHS_C + g2] =
            e_graph[g2] + e_graph[N_GRAPHS_C + g2] +
            e_graph[2 * N_GRAPHS_C + g2] + e_graph[3 * N_GRAPHS_C + g2];
}

// passB: block (b,s). Little's-law fix: each wave processes FOUR runs
// concurrently (k, k+16, k+32, k+48) -> 4 independent cnt loads, then 4
// independent uint4 record loads (64 B in flight vs 16 B) per inner
// iteration, feeding exec-masked DS chains. Clamped branchless indices keep
// all 4 loads issued even as shorter runs drain (re-reads last element,
// DS masked off -- harmless). Odd tails: lane 0, per run.
__global__ __launch_bounds__(TPBB) void passB(
    const uint2* __restrict__ records, int cap,
    const unsigned* __restrict__ cnt_table,
    unsigned* __restrict__ partial, int nblkA, int nb, int nslice)
{
    __shared__ unsigned acc[2 * CHUNK];   // [0..CHUNK): (fx,fy); [CHUNK..): (fz,0)

    int b = blockIdx.x / nslice;
    int s = blockIdx.x % nslice;
    int k0 = (int)((long long)s * nblkA / nslice);
    int k1 = (int)((long long)(s + 1) * nblkA / nslice);

    for (int i = threadIdx.x; i < 2 * CHUNK; i += TPBB) acc[i] = 0u;
    __syncthreads();

    unsigned lds_base = (unsigned)(size_t)&acc[0];
    int wid  = threadIdx.x >> 6;
    int lane = threadIdx.x & 63;

    for (int kb = k0 + wid; kb < k1; kb += 64) {
        int ka = kb, kb_ = kb + 16, kc = kb + 32, kd = kb + 48;
        bool e1 = kb_ < k1, e2 = kc < k1, e3 = kd < k1;

        unsigned n0 = cnt_table[(size_t)ka * nb + b];
        unsigned n1 = e1 ? cnt_table[(size_t)kb_ * nb + b] : 0u;
        unsigned n2 = e2 ? cnt_table[(size_t)kc  * nb + b] : 0u;
        unsigned n3 = e3 ? cnt_table[(size_t)kd  * nb + b] : 0u;

        const uint2* r0 = records + ((size_t)ka * nb + b) * cap;
        const uint2* r1 = e1 ? records + ((size_t)kb_ * nb + b) * cap : r0;
        const uint2* r2 = e2 ? records + ((size_t)kc  * nb + b) * cap : r0;
        const uint2* r3 = e3 ? records + ((size_t)kd  * nb + b) * cap : r0;
        const uint4* q0 = (const uint4*)r0;
        const uint4* q1 = (const uint4*)r1;
        const uint4* q2 = (const uint4*)r2;
        const uint4* q3 = (const uint4*)r3;

        unsigned h0 = n0 >> 1, h1 = n1 >> 1, h2 = n2 >> 1, h3 = n3 >> 1;
        unsigned hm = max(max(h0, h1), max(h2, h3));

        for (unsigned i = lane; i < hm; i += 64) {
            uint4 v0 = q0[h0 ? min(i, h0 - 1u) : 0u];
            uint4 v1 = q1[h1 ? min(i, h1 - 1u) : 0u];
            uint4 v2 = q2[h2 ? min(i, h2 - 1u) : 0u];
            uint4 v3 = q3[h3 ? min(i, h3 - 1u) : 0u];
            if (i < h0) ds_rec2(lds_base, v0);
            if (i < h1) ds_rec2(lds_base, v1);
            if (i < h2) ds_rec2(lds_base, v2);
            if (i < h3) ds_rec2(lds_base, v3);
        }
        if (lane == 0) {
            if (n0 & 1u) ds_rec1(lds_base, r0[n0 - 1]);
            if (n1 & 1u) ds_rec1(lds_base, r1[n1 - 1]);
            if (n2 & 1u) ds_rec1(lds_base, r2[n2 - 1]);
            if (n3 & 1u) ds_rec1(lds_base, r3[n3 - 1]);
        }
    }
    asm volatile("s_waitcnt lgkmcnt(0)" ::: "memory");
    __syncthreads();

    unsigned* dst = partial + (size_t)blockIdx.x * 2 * CHUNK;
    for (int i = threadIdx.x; i < 2 * CHUNK; i += TPBB) dst[i] = acc[i];
}

// fin_force: blocks [0,nfblk) reduce force partials; blocks [nfblk, nfblk+64)
// do the energy reduction (one wave per graph) -- fuses the old fin_energy
// launch away.
__global__ __launch_bounds__(256) void fin_force(
    const unsigned* __restrict__ partial, const float* __restrict__ ovf,
    const float* __restrict__ e_part,
    float* __restrict__ force, float* __restrict__ energy,
    int n_atoms, int nslice, int nblkA, int nfblk)
{
    if ((int)blockIdx.x >= nfblk) {
        int g = (blockIdx.x - nfblk) * 4 + (threadIdx.x >> 6);   // graph per wave
        int lane = threadIdx.x & 63;
        float s = 0.f;
        for (int k = lane; k < nblkA; k += 64)
            s += e_part[(size_t)k * N_GRAPHS_C + g];
        for (int off = 32; off > 0; off >>= 1) s += __shfl_down(s, off, 64);
        if (lane == 0) energy[g] = s;
        return;
    }
    int a = blockIdx.x * 256 + threadIdx.x;
    if (a >= n_atoms) return;
    int b = a >> CHUNK_LOG, l = a & (CHUNK - 1);
    float fx = ovf[3 * a + 0], fy = ovf[3 * a + 1], fz = ovf[3 * a + 2];
    const unsigned* p = partial + (size_t)b * nslice * 2 * CHUNK + l;
    for (int s = 0; s < nslice; ++s) {
        const unsigned* ps = p + (size_t)s * 2 * CHUNK;
        float2 f1 = __half22float2(__builtin_bit_cast(__half2, ps[0]));
        float2 f2 = __half22float2(__builtin_bit_cast(__half2, ps[CHUNK]));
        fx += f1.x; fy += f1.y; fz += f2.x;
    }
    force[3 * a + 0] = fx;
    force[3 * a + 1] = fy;
    force[3 * a + 2] = fz;
}

// ================= fallback: round-3 chunk-scan path =================
__global__ __launch_bounds__(1024) void chunk_kernel(
    const float* __restrict__ dij, const float* __restrict__ q,
    const float* __restrict__ g_ewald,
    const int* __restrict__ row, const int* __restrict__ col,
    float* __restrict__ partial, int n_edges, int n_chunks, int n_slices)
{
    __shared__ float acc[CHUNK * 4];
    int c = blockIdx.x % n_chunks;
    int p = blockIdx.x / n_chunks;
    int cbase = c << CHUNK_LOG;
    for (int i = threadIdx.x; i < CHUNK * 4; i += 1024) acc[i] = 0.f;
    __syncthreads();
    const float gA = g_ewald[0] * 1e-10f;
    int n4 = (n_edges + 3) >> 2;
    int g0 = (int)((long long)p * n4 / n_slices);
    int g1 = (int)((long long)(p + 1) * n4 / n_slices);
    const int4* row4 = (const int4*)row;
    const int4* col4 = (const int4*)col;
    for (int g = g0 + threadIdx.x; g < g1; g += 1024) {
        int4 r4 = row4[g];
        int4 c4 = col4[g];
        int rr[4] = {r4.x, r4.y, r4.z, r4.w};
        int cc[4] = {c4.x, c4.y, c4.z, c4.w};
        #pragma unroll
        for (int j = 0; j < 4; ++j) {
            int e = 4 * g + j;
            if (e >= n_edges) break;
            int rl = rr[j] - cbase;
            int cl = cc[j] - cbase;
            bool hr = (unsigned)rl < (unsigned)CHUNK;
            bool hc = (unsigned)cl < (unsigned)CHUNK;
            if (!(hr || hc)) continue;
            float fx, fy, fz, ec;
            edge_math(dij[3 * e], dij[3 * e + 1], dij[3 * e + 2],
                      q[rr[j]], q[cc[j]], gA, fx, fy, fz, ec);
            if (hr) {
                atomicAdd(&acc[4 * rl + 0], fx);
                atomicAdd(&acc[4 * rl + 1], fy);
                atomicAdd(&acc[4 * rl + 2], fz);
                atomicAdd(&acc[4 * rl + 3], ec);
            }
            if (hc) {
                atomicAdd(&acc[4 * cl + 0], -fx);
                atomicAdd(&acc[4 * cl + 1], -fy);
                atomicAdd(&acc[4 * cl + 2], -fz);
            }
        }
    }
    __syncthreads();
    float4* dst = (float4*)partial + (size_t)(c * n_slices + p) * CHUNK;
    const float4* src = (const float4*)acc;
    for (int i = threadIdx.x; i < CHUNK; i += 1024) dst[i] = src[i];
}

__global__ __launch_bounds__(256) void finalize_kernel(
    const float* __restrict__ partial, const int* __restrict__ batch,
    float* __restrict__ energy, float* __restrict__ force,
    int n_atoms, int n_slices)
{
    int i = blockIdx.x * blockDim.x + threadIdx.x;
    float fx = 0.f, fy = 0.f, fz = 0.f, en = 0.f;
    if (i < n_atoms) {
        int c = i >> CHUNK_LOG;
        int l = i & (CHUNK - 1);
        const float4* base = (const float4*)partial + (size_t)c * n_slices * CHUNK + l;
        for (int p = 0; p < n_slices; ++p) {
            float4 v = base[(size_t)p * CHUNK];
            fx += v.x; fy += v.y; fz += v.z; en += v.w;
        }
        force[3 * i + 0] = fx;
        force[3 * i + 1] = fy;
        force[3 * i + 2] = fz;
    }
    int ic = i < n_atoms ? i : (n_atoms - 1);
    int b = batch[ic];
    float v = (i < n_atoms) ? en : 0.0f;
    int b0 = __shfl(b, 0, 64);
    unsigned long long m = __ballot(b == b0);
    if (m == ~0ull) {
        for (int off = 32; off > 0; off >>= 1)
            v += __shfl_down(v, off, 64);
        if ((threadIdx.x & 63) == 0) atomicAdd(&energy[b0], v);
    } else {
        atomicAdd(&energy[b], v);
    }
}

extern "C" void kernel_launch(void* const* d_in, const int* in_sizes, int n_in,
                              void* d_out, int out_size, void* d_ws, size_t ws_size,
                              hipStream_t stream) {
    const float* dij     = (const float*)d_in[0];
    const float* q       = (const float*)d_in[1];
    const float* g_ewald = (const float*)d_in[2];
    const int*   row     = (const int*)d_in[3];
    const int*   col     = (const int*)d_in[4];
    const int*   batch   = (const int*)d_in[5];

    int n_edges = in_sizes[0] / 3;
    int n_atoms = in_sizes[1];

    float* energy = (float*)d_out;               // [256]
    float* force  = (float*)d_out + N_GRAPHS_C;  // [n_atoms*3]

    int nb = (n_atoms + CHUNK - 1) >> CHUNK_LOG;            // 25
    int n4 = n_edges >> 2;

    size_t sz_partial = (size_t)nb * NSLICE * 2 * CHUNK * sizeof(unsigned); // 32.8 MB
    size_t sz_ovf     = (size_t)3 * n_atoms * sizeof(float);
    size_t sz_qg      = (size_t)n_atoms * sizeof(float2);

    // Adaptive tile selection: prefer tile_g=1024 with cap>=384 (mean 327.7 +
    // 3.2 sigma; rare overflow goes through ovf atomics, still correct). Fall
    // back to tile_g=2048 / cap>=768, then to the chunk-scan path.
    const int  tile_sel[2]   = {1024, 2048};
    const int  mincap_sel[2] = {384, 768};
    const int  capmax_sel[2] = {512, 1024};

    int tile_g = 0, cap = 0, nblkA = 0;
    size_t sz_epart = 0, sz_cnt = 0;
    for (int t = 0; t < 2 && tile_g == 0; ++t) {
        int nba = (n4 + tile_sel[t] - 1) / tile_sel[t];
        size_t se = (size_t)nba * N_GRAPHS_C * sizeof(float);
        size_t sc = (size_t)nba * nb * sizeof(unsigned);
        size_t fixed = ((sz_partial + 255) & ~(size_t)255) +
                       ((se         + 255) & ~(size_t)255) +
                       ((sc         + 255) & ~(size_t)255) +
                       ((sz_ovf     + 255) & ~(size_t)255) +
                       ((sz_qg      + 255) & ~(size_t)255) + 512;
        if ((long long)ws_size > (long long)fixed) {
            long long c = ((long long)ws_size - (long long)fixed) /
                          ((long long)nba * nb * 8);
            c = (c / 32) * 32;
            if (c > capmax_sel[t]) c = capmax_sel[t];
            if (c >= mincap_sel[t]) {
                tile_g = tile_sel[t]; cap = (int)c; nblkA = nba;
                sz_epart = se; sz_cnt = sc;
            }
        }
    }

    bool fast = (nb <= MAXB) && ((n_edges & 3) == 0) && (tile_g > 0);

    if (fast) {
        char* ws = (char*)d_ws;
        size_t off = 0;
        uint2*    records  = (uint2*)(ws + off);
        off += (size_t)nblkA * nb * cap * 8;   off = (off + 255) & ~(size_t)255;
        unsigned* partial  = (unsigned*)(ws + off);
        off += sz_partial;                     off = (off + 255) & ~(size_t)255;
        float*    e_part   = (float*)(ws + off);
        off += sz_epart;                       off = (off + 255) & ~(size_t)255;
        unsigned* cnt_tab  = (unsigned*)(ws + off);
        off += sz_cnt;                         off = (off + 255) & ~(size_t)255;
        float*    ovf      = (float*)(ws + off);
        off += sz_ovf;                         off = (off + 255) & ~(size_t)255;
        float2*   qg       = (float2*)(ws + off);

        prep_qg<<<(n_atoms + 255) / 256, 256, 0, stream>>>(q, batch, qg, ovf, n_atoms);

        passA<<<nblkA, TPA, 0, stream>>>(
            dij, qg, g_ewald, row, col,
            records, cap, cnt_tab, e_part, ovf, n_edges, nb, tile_g);

        passB<<<nb * NSLICE, TPBB, 0, stream>>>(
            records, cap, cnt_tab, partial, nblkA, nb, NSLICE);

        int nfblk = (n_atoms + 255) / 256;
        fin_force<<<nfblk + N_GRAPHS_C / 4, 256, 0, stream>>>(
            partial, ovf, e_part, force, energy, n_atoms, NSLICE, nblkA, nfblk);
    } else {
        size_t need_chunk = (size_t)nb * NSLICE_FB * CHUNK * 4 * sizeof(float);
        if (ws_size >= need_chunk) {
            hipMemsetAsync(d_out, 0, N_GRAPHS_C * sizeof(float), stream);
            chunk_kernel<<<nb * NSLICE_FB, 1024, 0, stream>>>(
                dij, q, g_ewald, row, col, (float*)d_ws, n_edges, nb, NSLICE_FB);
            finalize_kernel<<<(n_atoms + 255) / 256, 256, 0, stream>>>(
                (const float*)d_ws, batch, energy, force, n_atoms, NSLICE_FB);
        }
    }
}

// Round 4
// 398.024 us; speedup vs baseline: 1.2416x; 1.2416x over previous
//
#include <hip/hip_runtime.h>
#include <hip/hip_fp16.h>

#define N_GRAPHS_C 256
#define CHUNK_LOG 12
#define CHUNK (1 << CHUNK_LOG)   // 4096 atoms per bucket
#define MAXB 64
#define NSLICE 12                // passB slices per bucket (48 KB LDS -> 3 blocks/CU)
#define NSLICE_FB 10
#define TPA 256
#define TPBB 512
#define FP_SCALE 1024.0f
#define FP_INV   (1.0f / 1024.0f)

// ---------------- shared per-edge math ----------------
// Units: Angstrom, electron charge, eV (avoids fp32 denormals from the
// reference's SI-unit charges; algebraically identical).
__device__ __forceinline__ void edge_math(
    float dx, float dy, float dz, float qr, float qc, float gA,
    float& fx, float& fy, float& fz, float& ecoul)
{
    const float KEV = (float)(8987551792.3 * 1.602176634e-9); // 14.3996 eV*A/e^2
    float r2 = dx * dx + dy * dy + dz * dz;
    float inv_r = rsqrtf(r2);
    float rA = r2 * inv_r;

    float pref = KEV * qr * qc * inv_r;

    float damp = 1.0f;
    if (rA < 2.2f)
        damp = __expf(-18.7f * (2.2f - rA) * (1.0f / 2.2f));

    float grij = gA * rA;
    float expm2 = __expf(-grij * grij);
    float t = 1.0f / (1.0f + 0.3275911f * grij);
    float erfc = t * (0.254829592f +
                 t * (-0.284496736f +
                 t * (1.421413741f +
                 t * (-1.453152027f +
                 t * 1.061405429f)))) * expm2;

    ecoul = pref * (0.5f * damp + (erfc - 1.0f));
    float S = damp + erfc + 2.0f * grij * expm2 - 1.0f;
    float fs = pref * S * (inv_r * inv_r);
    fx = dx * fs; fy = dy * fs; fz = dz * fs;
}

__device__ __forceinline__ uint2 pack_rec(float fx, float fy, float fz, unsigned lid)
{
    uint2 u;
    u.x = __builtin_bit_cast(unsigned, __floats2half2_rn(fx, fy));
    u.y = (__builtin_bit_cast(unsigned, __floats2half2_rn(fz, 0.0f)) & 0xFFFFu) |
          (lid << 16);
    return u;
}

// Ballot-aggregated slot allocation: group same-bucket lanes (bucket < 64 ->
// 6 ballots), one leader atomicAdd per group, broadcast base, slot = base+rank.
// Cuts LDS rank-atomic lane-ops from 1/lane to ~distinct-buckets/wave (~0.37).
__device__ __forceinline__ unsigned alloc_slot(unsigned* cnt, int bkt, int lane)
{
    unsigned long long m = __ballot(1);           // active lanes
    #pragma unroll
    for (int bit = 0; bit < 6; ++bit) {
        unsigned long long bb = __ballot((bkt >> bit) & 1);
        m &= ((bkt >> bit) & 1) ? bb : ~bb;
    }
    int leader = __ffsll((unsigned long long)m) - 1;
    unsigned rank = (unsigned)__popcll(m & ((1ull << lane) - 1ull));
    unsigned base = 0;
    if (lane == leader)
        base = atomicAdd(&cnt[bkt], (unsigned)__popcll(m));
    base = (unsigned)__shfl((int)base, leader, 64);
    return base + rank;
}

// passB record accumulate: f16 record -> i32 fixed-point (scale 2^10) into
// three full-width planes via native integer LDS atomics (ds_add_u32).
__device__ __forceinline__ void acc_rec(int* acc, unsigned w0, unsigned w1)
{
    float2 xy = __half22float2(__builtin_bit_cast(__half2, w0));
    float fz = __half2float(__builtin_bit_cast(__half2, w1).x);   // low half
    unsigned idx = w1 >> 16;
    atomicAdd(&acc[idx],             __float2int_rn(xy.x * FP_SCALE));
    atomicAdd(&acc[CHUNK + idx],     __float2int_rn(xy.y * FP_SCALE));
    atomicAdd(&acc[2 * CHUNK + idx], __float2int_rn(fz   * FP_SCALE));
}

// prep: fuse q[] and batch[] into one 8 B table so passA does 2 scattered
// gathers per edge instead of 3. Also zeroes ovf[] (replaces a memset launch).
__global__ __launch_bounds__(256) void prep_qg(
    const float* __restrict__ q, const int* __restrict__ batch,
    float2* __restrict__ qg, float* __restrict__ ovf, int n_atoms)
{
    int i = blockIdx.x * 256 + threadIdx.x;
    if (i < n_atoms) {
        qg[i] = make_float2(q[i], __int_as_float(batch[i]));
        ovf[3 * i + 0] = 0.f;
        ovf[3 * i + 1] = 0.f;
        ovf[3 * i + 2] = 0.f;
    }
}

// ================= fast path =================
// passA: dense single sweep. Per edge: 2 scattered 8 B gathers (qg[r], qg[c]),
// ~50 VALU of math, 1 LDS energy atomic, ~0.73 aggregated rank atomics, 2
// scattered 8 B record stores. 2-deep software pipeline on the gathers.
__global__ __launch_bounds__(TPA) void passA(
    const float* __restrict__ dij, const float2* __restrict__ qg,
    const float* __restrict__ g_ewald,
    const int* __restrict__ row, const int* __restrict__ col,
    uint2* __restrict__ records, int cap,
    unsigned* __restrict__ cnt_table,
    float* __restrict__ e_part,
    float* __restrict__ ovf,
    int n_edges, int nb, int tile_g)
{
    __shared__ unsigned cnt[MAXB];
    __shared__ float e_graph[4 * N_GRAPHS_C];   // per-wave replicas

    int tid = threadIdx.x;
    int lane = tid & 63;
    if (tid < MAXB) cnt[tid] = 0u;
    for (int i = tid; i < 4 * N_GRAPHS_C; i += TPA) e_graph[i] = 0.f;
    __syncthreads();

    float* e_my = &e_graph[(tid >> 6) * N_GRAPHS_C];

    int n4 = n_edges >> 2;
    int g0 = blockIdx.x * tile_g;
    int g1 = min(g0 + tile_g, n4);

    const int4* row4 = (const int4*)row;
    const int4* col4 = (const int4*)col;
    const float4* dij4 = (const float4*)dij;

    const float gA = g_ewald[0] * 1e-10f;    // 1/m -> 1/Angstrom
    size_t blk_base = (size_t)blockIdx.x * nb * cap;

    int g = g0 + tid;
    int4 r_cur = make_int4(0, 0, 0, 0), c_cur = make_int4(0, 0, 0, 0);
    int4 r_nxt = make_int4(0, 0, 0, 0), c_nxt = make_int4(0, 0, 0, 0);
    float2 vr_cur[4], vc_cur[4];

    if (g < g1) {
        r_cur = row4[g]; c_cur = col4[g];
        vr_cur[0] = qg[r_cur.x]; vc_cur[0] = qg[c_cur.x];
        vr_cur[1] = qg[r_cur.y]; vc_cur[1] = qg[c_cur.y];
        vr_cur[2] = qg[r_cur.z]; vc_cur[2] = qg[c_cur.z];
        vr_cur[3] = qg[r_cur.w]; vc_cur[3] = qg[c_cur.w];
    }
    if (g + TPA < g1) { r_nxt = row4[g + TPA]; c_nxt = col4[g + TPA]; }

    while (g < g1) {
        int gn = g + TPA;

        // issue NEXT group's gathers now (indices prefetched last iteration;
        // zero-init indices make these qg[0] loads when past the end: harmless)
        float2 vr_n[4], vc_n[4];
        vr_n[0] = qg[r_nxt.x]; vc_n[0] = qg[c_nxt.x];
        vr_n[1] = qg[r_nxt.y]; vc_n[1] = qg[c_nxt.y];
        vr_n[2] = qg[r_nxt.z]; vc_n[2] = qg[c_nxt.z];
        vr_n[3] = qg[r_nxt.w]; vc_n[3] = qg[c_nxt.w];

        // prefetch indices two groups ahead (bounds-guarded)
        int4 r_n2 = make_int4(0, 0, 0, 0), c_n2 = make_int4(0, 0, 0, 0);
        if (gn + TPA < g1) { r_n2 = row4[gn + TPA]; c_n2 = col4[gn + TPA]; }

        float4 d0 = dij4[3 * g + 0];
        float4 d1 = dij4[3 * g + 1];
        float4 d2 = dij4[3 * g + 2];
        float ex[4] = {d0.x, d0.w, d1.z, d2.y};
        float ey[4] = {d0.y, d1.x, d1.w, d2.z};
        float ez[4] = {d0.z, d1.y, d2.x, d2.w};
        int rr[4] = {r_cur.x, r_cur.y, r_cur.z, r_cur.w};
        int cc[4] = {c_cur.x, c_cur.y, c_cur.z, c_cur.w};

        #pragma unroll
        for (int j = 0; j < 4; ++j) {
            int r = rr[j], c = cc[j];
            float fx, fy, fz, ec;
            edge_math(ex[j], ey[j], ez[j], vr_cur[j].x, vc_cur[j].x, gA,
                      fx, fy, fz, ec);

            atomicAdd(&e_my[__float_as_int(vr_cur[j].y)], ec);

            int br = r >> CHUNK_LOG, bc = c >> CHUNK_LOG;
            unsigned pr = alloc_slot(cnt, br, lane);
            unsigned pc = alloc_slot(cnt, bc, lane);
            if (pr < (unsigned)cap)
                records[blk_base + (size_t)br * cap + pr] =
                    pack_rec(fx, fy, fz, (unsigned)(r & (CHUNK - 1)));
            else {
                atomicAdd(&ovf[3 * r + 0], fx);
                atomicAdd(&ovf[3 * r + 1], fy);
                atomicAdd(&ovf[3 * r + 2], fz);
            }
            if (pc < (unsigned)cap)
                records[blk_base + (size_t)bc * cap + pc] =
                    pack_rec(-fx, -fy, -fz, (unsigned)(c & (CHUNK - 1)));
            else {
                atomicAdd(&ovf[3 * c + 0], -fx);
                atomicAdd(&ovf[3 * c + 1], -fy);
                atomicAdd(&ovf[3 * c + 2], -fz);
            }
        }

        g = gn;
        r_cur = r_nxt; c_cur = c_nxt;
        r_nxt = r_n2;  c_nxt = c_n2;
        #pragma unroll
        for (int j = 0; j < 4; ++j) { vr_cur[j] = vr_n[j]; vc_cur[j] = vc_n[j]; }
    }
    __syncthreads();

    if (tid < nb) cnt_table[(size_t)blockIdx.x * nb + tid] = min(cnt[tid], (unsigned)cap);
    for (int g2 = tid; g2 < N_GRAPHS_C; g2 += TPA)
        e_part[(size_t)blockIdx.x * N_GRAPHS_C + g2] =
            e_graph[g2] + e_graph[N_GRAPHS_C + g2] +
            e_graph[2 * N_GRAPHS_C + g2] + e_graph[3 * N_GRAPHS_C + g2];
}

// passB: block (b,s); each wave takes whole runs. Accumulates into three
// full-width i32 fixed-point planes (48 KB) via native ds_add_u32 -- exact,
// deterministic, and (hypothesis) full-rate vs the pk_f16 slow path.
__global__ __launch_bounds__(TPBB) void passB(
    const uint2* __restrict__ records, int cap,
    const unsigned* __restrict__ cnt_table,
    int* __restrict__ partial, int nblkA, int nb, int nslice)
{
    __shared__ int acc[3 * CHUNK];

    int b = blockIdx.x / nslice;
    int s = blockIdx.x % nslice;
    int k0 = (int)((long long)s * nblkA / nslice);
    int k1 = (int)((long long)(s + 1) * nblkA / nslice);

    for (int i = threadIdx.x; i < 3 * CHUNK; i += TPBB) acc[i] = 0;
    __syncthreads();

    int wid  = threadIdx.x >> 6;
    int lane = threadIdx.x & 63;

    for (int k = k0 + wid; k < k1; k += TPBB / 64) {
        unsigned n = cnt_table[(size_t)k * nb + b];       // wave-uniform
        const uint2* rec = records + ((size_t)k * nb + b) * cap;
        const uint4* rec4 = (const uint4*)rec;            // cap%32==0 -> 256B aligned
        unsigned nh = n >> 1;
        for (unsigned i = lane; i < nh; i += 64) {
            uint4 v = rec4[i];
            acc_rec(acc, v.x, v.y);
            acc_rec(acc, v.z, v.w);
        }
        if ((n & 1u) && lane == 0) {                      // odd tail record
            uint2 t = rec[n - 1];
            acc_rec(acc, t.x, t.y);
        }
    }
    __syncthreads();

    int* dst = partial + (size_t)blockIdx.x * 3 * CHUNK;
    for (int i = threadIdx.x; i < 3 * CHUNK; i += TPBB) dst[i] = acc[i];
}

// fin_force: blocks [0,nfblk) reduce force partials (exact integer sums);
// blocks [nfblk, nfblk+64) do the energy reduction (one wave per graph).
__global__ __launch_bounds__(256) void fin_force(
    const int* __restrict__ partial, const float* __restrict__ ovf,
    const float* __restrict__ e_part,
    float* __restrict__ force, float* __restrict__ energy,
    int n_atoms, int nslice, int nblkA, int nfblk)
{
    if ((int)blockIdx.x >= nfblk) {
        int g = (blockIdx.x - nfblk) * 4 + (threadIdx.x >> 6);   // graph per wave
        int lane = threadIdx.x & 63;
        float s = 0.f;
        for (int k = lane; k < nblkA; k += 64)
            s += e_part[(size_t)k * N_GRAPHS_C + g];
        for (int off = 32; off > 0; off >>= 1) s += __shfl_down(s, off, 64);
        if (lane == 0) energy[g] = s;
        return;
    }
    int a = blockIdx.x * 256 + threadIdx.x;
    if (a >= n_atoms) return;
    int b = a >> CHUNK_LOG, l = a & (CHUNK - 1);
    long long sx = 0, sy = 0, sz = 0;
    const int* p = partial + (size_t)b * nslice * 3 * CHUNK + l;
    for (int s = 0; s < nslice; ++s) {
        const int* ps = p + (size_t)s * 3 * CHUNK;
        sx += ps[0]; sy += ps[CHUNK]; sz += ps[2 * CHUNK];
    }
    force[3 * a + 0] = ovf[3 * a + 0] + (float)sx * FP_INV;
    force[3 * a + 1] = ovf[3 * a + 1] + (float)sy * FP_INV;
    force[3 * a + 2] = ovf[3 * a + 2] + (float)sz * FP_INV;
}

// ================= fallback: chunk-scan path =================
__global__ __launch_bounds__(1024) void chunk_kernel(
    const float* __restrict__ dij, const float* __restrict__ q,
    const float* __restrict__ g_ewald,
    const int* __restrict__ row, const int* __restrict__ col,
    float* __restrict__ partial, int n_edges, int n_chunks, int n_slices)
{
    __shared__ float acc[CHUNK * 4];
    int c = blockIdx.x % n_chunks;
    int p = blockIdx.x / n_chunks;
    int cbase = c << CHUNK_LOG;
    for (int i = threadIdx.x; i < CHUNK * 4; i += 1024) acc[i] = 0.f;
    __syncthreads();
    const float gA = g_ewald[0] * 1e-10f;
    int n4 = (n_edges + 3) >> 2;
    int g0 = (int)((long long)p * n4 / n_slices);
    int g1 = (int)((long long)(p + 1) * n4 / n_slices);
    const int4* row4 = (const int4*)row;
    const int4* col4 = (const int4*)col;
    for (int g = g0 + threadIdx.x; g < g1; g += 1024) {
        int4 r4 = row4[g];
        int4 c4 = col4[g];
        int rr[4] = {r4.x, r4.y, r4.z, r4.w};
        int cc[4] = {c4.x, c4.y, c4.z, c4.w};
        #pragma unroll
        for (int j = 0; j < 4; ++j) {
            int e = 4 * g + j;
            if (e >= n_edges) break;
            int rl = rr[j] - cbase;
            int cl = cc[j] - cbase;
            bool hr = (unsigned)rl < (unsigned)CHUNK;
            bool hc = (unsigned)cl < (unsigned)CHUNK;
            if (!(hr || hc)) continue;
            float fx, fy, fz, ec;
            edge_math(dij[3 * e], dij[3 * e + 1], dij[3 * e + 2],
                      q[rr[j]], q[cc[j]], gA, fx, fy, fz, ec);
            if (hr) {
                atomicAdd(&acc[4 * rl + 0], fx);
                atomicAdd(&acc[4 * rl + 1], fy);
                atomicAdd(&acc[4 * rl + 2], fz);
                atomicAdd(&acc[4 * rl + 3], ec);
            }
            if (hc) {
                atomicAdd(&acc[4 * cl + 0], -fx);
                atomicAdd(&acc[4 * cl + 1], -fy);
                atomicAdd(&acc[4 * cl + 2], -fz);
            }
        }
    }
    __syncthreads();
    float4* dst = (float4*)partial + (size_t)(c * n_slices + p) * CHUNK;
    const float4* src = (const float4*)acc;
    for (int i = threadIdx.x; i < CHUNK; i += 1024) dst[i] = src[i];
}

__global__ __launch_bounds__(256) void finalize_kernel(
    const float* __restrict__ partial, const int* __restrict__ batch,
    float* __restrict__ energy, float* __restrict__ force,
    int n_atoms, int n_slices)
{
    int i = blockIdx.x * blockDim.x + threadIdx.x;
    float fx = 0.f, fy = 0.f, fz = 0.f, en = 0.f;
    if (i < n_atoms) {
        int c = i >> CHUNK_LOG;
        int l = i & (CHUNK - 1);
        const float4* base = (const float4*)partial + (size_t)c * n_slices * CHUNK + l;
        for (int p = 0; p < n_slices; ++p) {
            float4 v = base[(size_t)p * CHUNK];
            fx += v.x; fy += v.y; fz += v.z; en += v.w;
        }
        force[3 * i + 0] = fx;
        force[3 * i + 1] = fy;
        force[3 * i + 2] = fz;
    }
    int ic = i < n_atoms ? i : (n_atoms - 1);
    int b = batch[ic];
    float v = (i < n_atoms) ? en : 0.0f;
    int b0 = __shfl(b, 0, 64);
    unsigned long long m = __ballot(b == b0);
    if (m == ~0ull) {
        for (int off = 32; off > 0; off >>= 1)
            v += __shfl_down(v, off, 64);
        if ((threadIdx.x & 63) == 0) atomicAdd(&energy[b0], v);
    } else {
        atomicAdd(&energy[b], v);
    }
}

extern "C" void kernel_launch(void* const* d_in, const int* in_sizes, int n_in,
                              void* d_out, int out_size, void* d_ws, size_t ws_size,
                              hipStream_t stream) {
    const float* dij     = (const float*)d_in[0];
    const float* q       = (const float*)d_in[1];
    const float* g_ewald = (const float*)d_in[2];
    const int*   row     = (const int*)d_in[3];
    const int*   col     = (const int*)d_in[4];
    const int*   batch   = (const int*)d_in[5];

    int n_edges = in_sizes[0] / 3;
    int n_atoms = in_sizes[1];

    float* energy = (float*)d_out;               // [256]
    float* force  = (float*)d_out + N_GRAPHS_C;  // [n_atoms*3]

    int nb = (n_atoms + CHUNK - 1) >> CHUNK_LOG;            // 49
    int n4 = n_edges >> 2;

    size_t sz_partial = (size_t)nb * NSLICE * 3 * CHUNK * sizeof(int);  // ~29 MB
    size_t sz_ovf     = (size_t)3 * n_atoms * sizeof(float);
    size_t sz_qg      = (size_t)n_atoms * sizeof(float2);

    // Adaptive tile selection. nb=49 buckets: tile 1024 -> mean 167/run,
    // sigma ~13 -> cap 256 is +7 sigma; tile 2048 -> mean 334, cap 512 = +10.
    // Rare overflow goes through ovf atomics (still correct).
    const int  tile_sel[2]   = {1024, 2048};
    const int  mincap_sel[2] = {224, 416};
    const int  capmax_sel[2] = {256, 512};

    int tile_g = 0, cap = 0, nblkA = 0;
    size_t sz_epart = 0, sz_cnt = 0;
    for (int t = 0; t < 2 && tile_g == 0; ++t) {
        int nba = (n4 + tile_sel[t] - 1) / tile_sel[t];
        size_t se = (size_t)nba * N_GRAPHS_C * sizeof(float);
        size_t sc = (size_t)nba * nb * sizeof(unsigned);
        size_t fixed = ((sz_partial + 255) & ~(size_t)255) +
                       ((se         + 255) & ~(size_t)255) +
                       ((sc         + 255) & ~(size_t)255) +
                       ((sz_ovf     + 255) & ~(size_t)255) +
                       ((sz_qg      + 255) & ~(size_t)255) + 512;
        if ((long long)ws_size > (long long)fixed) {
            long long c = ((long long)ws_size - (long long)fixed) /
                          ((long long)nba * nb * 8);
            c = (c / 32) * 32;
            if (c > capmax_sel[t]) c = capmax_sel[t];
            if (c >= mincap_sel[t]) {
                tile_g = tile_sel[t]; cap = (int)c; nblkA = nba;
                sz_epart = se; sz_cnt = sc;
            }
        }
    }

    bool fast = (nb <= MAXB) && ((n_edges & 3) == 0) && (tile_g > 0);

    if (fast) {
        char* ws = (char*)d_ws;
        size_t off = 0;
        uint2*    records  = (uint2*)(ws + off);
        off += (size_t)nblkA * nb * cap * 8;   off = (off + 255) & ~(size_t)255;
        int*      partial  = (int*)(ws + off);
        off += sz_partial;                     off = (off + 255) & ~(size_t)255;
        float*    e_part   = (float*)(ws + off);
        off += sz_epart;                       off = (off + 255) & ~(size_t)255;
        unsigned* cnt_tab  = (unsigned*)(ws + off);
        off += sz_cnt;                         off = (off + 255) & ~(size_t)255;
        float*    ovf      = (float*)(ws + off);
        off += sz_ovf;                         off = (off + 255) & ~(size_t)255;
        float2*   qg       = (float2*)(ws + off);

        prep_qg<<<(n_atoms + 255) / 256, 256, 0, stream>>>(q, batch, qg, ovf, n_atoms);

        passA<<<nblkA, TPA, 0, stream>>>(
            dij, qg, g_ewald, row, col,
            records, cap, cnt_tab, e_part, ovf, n_edges, nb, tile_g);

        passB<<<nb * NSLICE, TPBB, 0, stream>>>(
            records, cap, cnt_tab, partial, nblkA, nb, NSLICE);

        int nfblk = (n_atoms + 255) / 256;
        fin_force<<<nfblk + N_GRAPHS_C / 4, 256, 0, stream>>>(
            partial, ovf, e_part, force, energy, n_atoms, NSLICE, nblkA, nfblk);
    } else {
        size_t need_chunk = (size_t)nb * NSLICE_FB * CHUNK * 4 * sizeof(float);
        if (ws_size >= need_chunk) {
            hipMemsetAsync(d_out, 0, N_GRAPHS_C * sizeof(float), stream);
            chunk_kernel<<<nb * NSLICE_FB, 1024, 0, stream>>>(
                dij, q, g_ewald, row, col, (float*)d_ws, n_edges, nb, NSLICE_FB);
            finalize_kernel<<<(n_atoms + 255) / 256, 256, 0, stream>>>(
                (const float*)d_ws, batch, energy, force, n_atoms, NSLICE_FB);
        }
    }
}

// Round 5
// 397.040 us; speedup vs baseline: 1.2447x; 1.0025x over previous
//
#include <hip/hip_runtime.h>
#include <hip/hip_fp16.h>

#define N_GRAPHS_C 256
#define CHUNK_LOG 12
#define CHUNK (1 << CHUNK_LOG)   // 4096 atoms per bucket
#define MAXB 64
#define NSLICE 12                // passB slices per bucket (48 KB LDS -> 3 blocks/CU)
#define NSLICE_FB 10
#define TPA 256
#define TPBB 512
#define FP_SCALE 1024.0f
#define FP_INV   (1.0f / 1024.0f)

// ---------------- shared per-edge math ----------------
// Units: Angstrom, electron charge, eV (avoids fp32 denormals from the
// reference's SI-unit charges; algebraically identical).
__device__ __forceinline__ void edge_math(
    float dx, float dy, float dz, float qr, float qc, float gA,
    float& fx, float& fy, float& fz, float& ecoul)
{
    const float KEV = (float)(8987551792.3 * 1.602176634e-9); // 14.3996 eV*A/e^2
    float r2 = dx * dx + dy * dy + dz * dz;
    float inv_r = rsqrtf(r2);
    float rA = r2 * inv_r;

    float pref = KEV * qr * qc * inv_r;

    float damp = 1.0f;
    if (rA < 2.2f)
        damp = __expf(-18.7f * (2.2f - rA) * (1.0f / 2.2f));

    float grij = gA * rA;
    float expm2 = __expf(-grij * grij);
    float t = 1.0f / (1.0f + 0.3275911f * grij);
    float erfc = t * (0.254829592f +
                 t * (-0.284496736f +
                 t * (1.421413741f +
                 t * (-1.453152027f +
                 t * 1.061405429f)))) * expm2;

    ecoul = pref * (0.5f * damp + (erfc - 1.0f));
    float S = damp + erfc + 2.0f * grij * expm2 - 1.0f;
    float fs = pref * S * (inv_r * inv_r);
    fx = dx * fs; fy = dy * fs; fz = dz * fs;
}

__device__ __forceinline__ uint2 pack_rec(float fx, float fy, float fz, unsigned lid)
{
    uint2 u;
    u.x = __builtin_bit_cast(unsigned, __floats2half2_rn(fx, fy));
    u.y = (__builtin_bit_cast(unsigned, __floats2half2_rn(fz, 0.0f)) & 0xFFFFu) |
          (lid << 16);
    return u;
}

// passB record accumulate: f16 record -> i32 fixed-point (scale 2^10) into
// three full-width planes via native integer LDS atomics (ds_add_u32).
__device__ __forceinline__ void acc_rec(int* acc, unsigned w0, unsigned w1)
{
    float2 xy = __half22float2(__builtin_bit_cast(__half2, w0));
    float fz = __half2float(__builtin_bit_cast(__half2, w1).x);   // low half
    unsigned idx = w1 >> 16;
    atomicAdd(&acc[idx],             __float2int_rn(xy.x * FP_SCALE));
    atomicAdd(&acc[CHUNK + idx],     __float2int_rn(xy.y * FP_SCALE));
    atomicAdd(&acc[2 * CHUNK + idx], __float2int_rn(fz   * FP_SCALE));
}

// prep: fuse q[] and batch[] into one 8 B table so passA does 2 scattered
// gathers per edge instead of 3. Also zeroes ovf[] (replaces a memset launch).
__global__ __launch_bounds__(256) void prep_qg(
    const float* __restrict__ q, const int* __restrict__ batch,
    float2* __restrict__ qg, float* __restrict__ ovf, int n_atoms)
{
    int i = blockIdx.x * 256 + threadIdx.x;
    if (i < n_atoms) {
        qg[i] = make_float2(q[i], __int_as_float(batch[i]));
        ovf[3 * i + 0] = 0.f;
        ovf[3 * i + 1] = 0.f;
        ovf[3 * i + 2] = 0.f;
    }
}

// ================= fast path =================
// passA: dense single sweep. Per edge: 2 scattered 8 B gathers (qg[r], qg[c]),
// ~50 VALU of math, 1 LDS energy atomic, 2 plain LDS rank atomics, 2 scattered
// 8 B record stores. 2-deep software pipeline on the gathers.
// (Ballot-aggregated rank alloc tried in r4: +28us VALU, no atomic win -- the
// LDS atomic pipe was never the wall. Reverted to plain atomicAdd.)
__global__ __launch_bounds__(TPA) void passA(
    const float* __restrict__ dij, const float2* __restrict__ qg,
    const float* __restrict__ g_ewald,
    const int* __restrict__ row, const int* __restrict__ col,
    uint2* __restrict__ records, int cap,
    unsigned* __restrict__ cnt_table,
    float* __restrict__ e_part,
    float* __restrict__ ovf,
    int n_edges, int nb, int tile_g)
{
    __shared__ unsigned cnt[MAXB];
    __shared__ float e_graph[4 * N_GRAPHS_C];   // per-wave replicas

    int tid = threadIdx.x;
    if (tid < MAXB) cnt[tid] = 0u;
    for (int i = tid; i < 4 * N_GRAPHS_C; i += TPA) e_graph[i] = 0.f;
    __syncthreads();

    float* e_my = &e_graph[(tid >> 6) * N_GRAPHS_C];

    int n4 = n_edges >> 2;
    int g0 = blockIdx.x * tile_g;
    int g1 = min(g0 + tile_g, n4);

    const int4* row4 = (const int4*)row;
    const int4* col4 = (const int4*)col;
    const float4* dij4 = (const float4*)dij;

    const float gA = g_ewald[0] * 1e-10f;    // 1/m -> 1/Angstrom
    size_t blk_base = (size_t)blockIdx.x * nb * cap;

    int g = g0 + tid;
    int4 r_cur = make_int4(0, 0, 0, 0), c_cur = make_int4(0, 0, 0, 0);
    int4 r_nxt = make_int4(0, 0, 0, 0), c_nxt = make_int4(0, 0, 0, 0);
    float2 vr_cur[4], vc_cur[4];

    if (g < g1) {
        r_cur = row4[g]; c_cur = col4[g];
        vr_cur[0] = qg[r_cur.x]; vc_cur[0] = qg[c_cur.x];
        vr_cur[1] = qg[r_cur.y]; vc_cur[1] = qg[c_cur.y];
        vr_cur[2] = qg[r_cur.z]; vc_cur[2] = qg[c_cur.z];
        vr_cur[3] = qg[r_cur.w]; vc_cur[3] = qg[c_cur.w];
    }
    if (g + TPA < g1) { r_nxt = row4[g + TPA]; c_nxt = col4[g + TPA]; }

    while (g < g1) {
        int gn = g + TPA;

        // issue NEXT group's gathers now (indices prefetched last iteration;
        // zero-init indices make these qg[0] loads when past the end: harmless)
        float2 vr_n[4], vc_n[4];
        vr_n[0] = qg[r_nxt.x]; vc_n[0] = qg[c_nxt.x];
        vr_n[1] = qg[r_nxt.y]; vc_n[1] = qg[c_nxt.y];
        vr_n[2] = qg[r_nxt.z]; vc_n[2] = qg[c_nxt.z];
        vr_n[3] = qg[r_nxt.w]; vc_n[3] = qg[c_nxt.w];

        // prefetch indices two groups ahead (bounds-guarded)
        int4 r_n2 = make_int4(0, 0, 0, 0), c_n2 = make_int4(0, 0, 0, 0);
        if (gn + TPA < g1) { r_n2 = row4[gn + TPA]; c_n2 = col4[gn + TPA]; }

        float4 d0 = dij4[3 * g + 0];
        float4 d1 = dij4[3 * g + 1];
        float4 d2 = dij4[3 * g + 2];
        float ex[4] = {d0.x, d0.w, d1.z, d2.y};
        float ey[4] = {d0.y, d1.x, d1.w, d2.z};
        float ez[4] = {d0.z, d1.y, d2.x, d2.w};
        int rr[4] = {r_cur.x, r_cur.y, r_cur.z, r_cur.w};
        int cc[4] = {c_cur.x, c_cur.y, c_cur.z, c_cur.w};

        #pragma unroll
        for (int j = 0; j < 4; ++j) {
            int r = rr[j], c = cc[j];
            float fx, fy, fz, ec;
            edge_math(ex[j], ey[j], ez[j], vr_cur[j].x, vc_cur[j].x, gA,
                      fx, fy, fz, ec);

            atomicAdd(&e_my[__float_as_int(vr_cur[j].y)], ec);

            int br = r >> CHUNK_LOG, bc = c >> CHUNK_LOG;
            unsigned pr = atomicAdd(&cnt[br], 1u);
            unsigned pc = atomicAdd(&cnt[bc], 1u);
            if (pr < (unsigned)cap)
                records[blk_base + (size_t)br * cap + pr] =
                    pack_rec(fx, fy, fz, (unsigned)(r & (CHUNK - 1)));
            else {
                atomicAdd(&ovf[3 * r + 0], fx);
                atomicAdd(&ovf[3 * r + 1], fy);
                atomicAdd(&ovf[3 * r + 2], fz);
            }
            if (pc < (unsigned)cap)
                records[blk_base + (size_t)bc * cap + pc] =
                    pack_rec(-fx, -fy, -fz, (unsigned)(c & (CHUNK - 1)));
            else {
                atomicAdd(&ovf[3 * c + 0], -fx);
                atomicAdd(&ovf[3 * c + 1], -fy);
                atomicAdd(&ovf[3 * c + 2], -fz);
            }
        }

        g = gn;
        r_cur = r_nxt; c_cur = c_nxt;
        r_nxt = r_n2;  c_nxt = c_n2;
        #pragma unroll
        for (int j = 0; j < 4; ++j) { vr_cur[j] = vr_n[j]; vc_cur[j] = vc_n[j]; }
    }
    __syncthreads();

    if (tid < nb) cnt_table[(size_t)blockIdx.x * nb + tid] = min(cnt[tid], (unsigned)cap);
    for (int g2 = tid; g2 < N_GRAPHS_C; g2 += TPA)
        e_part[(size_t)blockIdx.x * N_GRAPHS_C + g2] =
            e_graph[g2] + e_graph[N_GRAPHS_C + g2] +
            e_graph[2 * N_GRAPHS_C + g2] + e_graph[3 * N_GRAPHS_C + g2];
}

// passB: block (b,s); each wave takes whole runs. Accumulates into three
// full-width i32 fixed-point planes (48 KB) via native ds_add_u32 -- exact,
// deterministic, full-rate (r4: pk_f16 slow path was the passB wall).
__global__ __launch_bounds__(TPBB) void passB(
    const uint2* __restrict__ records, int cap,
    const unsigned* __restrict__ cnt_table,
    int* __restrict__ partial, int nblkA, int nb, int nslice)
{
    __shared__ int acc[3 * CHUNK];

    int b = blockIdx.x / nslice;
    int s = blockIdx.x % nslice;
    int k0 = (int)((long long)s * nblkA / nslice);
    int k1 = (int)((long long)(s + 1) * nblkA / nslice);

    for (int i = threadIdx.x; i < 3 * CHUNK; i += TPBB) acc[i] = 0;
    __syncthreads();

    int wid  = threadIdx.x >> 6;
    int lane = threadIdx.x & 63;

    for (int k = k0 + wid; k < k1; k += TPBB / 64) {
        unsigned n = cnt_table[(size_t)k * nb + b];       // wave-uniform
        const uint2* rec = records + ((size_t)k * nb + b) * cap;
        const uint4* rec4 = (const uint4*)rec;            // cap%32==0 -> 256B aligned
        unsigned nh = n >> 1;
        for (unsigned i = lane; i < nh; i += 64) {
            uint4 v = rec4[i];
            acc_rec(acc, v.x, v.y);
            acc_rec(acc, v.z, v.w);
        }
        if ((n & 1u) && lane == 0) {                      // odd tail record
            uint2 t = rec[n - 1];
            acc_rec(acc, t.x, t.y);
        }
    }
    __syncthreads();

    int* dst = partial + (size_t)blockIdx.x * 3 * CHUNK;
    for (int i = threadIdx.x; i < 3 * CHUNK; i += TPBB) dst[i] = acc[i];
}

// fin_force: blocks [0,nfblk) reduce force partials (exact integer sums);
// blocks [nfblk, nfblk+64) do the energy reduction (one wave per graph).
__global__ __launch_bounds__(256) void fin_force(
    const int* __restrict__ partial, const float* __restrict__ ovf,
    const float* __restrict__ e_part,
    float* __restrict__ force, float* __restrict__ energy,
    int n_atoms, int nslice, int nblkA, int nfblk)
{
    if ((int)blockIdx.x >= nfblk) {
        int g = (blockIdx.x - nfblk) * 4 + (threadIdx.x >> 6);   // graph per wave
        int lane = threadIdx.x & 63;
        float s = 0.f;
        for (int k = lane; k < nblkA; k += 64)
            s += e_part[(size_t)k * N_GRAPHS_C + g];
        for (int off = 32; off > 0; off >>= 1) s += __shfl_down(s, off, 64);
        if (lane == 0) energy[g] = s;
        return;
    }
    int a = blockIdx.x * 256 + threadIdx.x;
    if (a >= n_atoms) return;
    int b = a >> CHUNK_LOG, l = a & (CHUNK - 1);
    long long sx = 0, sy = 0, sz = 0;
    const int* p = partial + (size_t)b * nslice * 3 * CHUNK + l;
    for (int s = 0; s < nslice; ++s) {
        const int* ps = p + (size_t)s * 3 * CHUNK;
        sx += ps[0]; sy += ps[CHUNK]; sz += ps[2 * CHUNK];
    }
    force[3 * a + 0] = ovf[3 * a + 0] + (float)sx * FP_INV;
    force[3 * a + 1] = ovf[3 * a + 1] + (float)sy * FP_INV;
    force[3 * a + 2] = ovf[3 * a + 2] + (float)sz * FP_INV;
}

// ================= fallback: chunk-scan path =================
__global__ __launch_bounds__(1024) void chunk_kernel(
    const float* __restrict__ dij, const float* __restrict__ q,
    const float* __restrict__ g_ewald,
    const int* __restrict__ row, const int* __restrict__ col,
    float* __restrict__ partial, int n_edges, int n_chunks, int n_slices)
{
    __shared__ float acc[CHUNK * 4];
    int c = blockIdx.x % n_chunks;
    int p = blockIdx.x / n_chunks;
    int cbase = c << CHUNK_LOG;
    for (int i = threadIdx.x; i < CHUNK * 4; i += 1024) acc[i] = 0.f;
    __syncthreads();
    const float gA = g_ewald[0] * 1e-10f;
    int n4 = (n_edges + 3) >> 2;
    int g0 = (int)((long long)p * n4 / n_slices);
    int g1 = (int)((long long)(p + 1) * n4 / n_slices);
    const int4* row4 = (const int4*)row;
    const int4* col4 = (const int4*)col;
    for (int g = g0 + threadIdx.x; g < g1; g += 1024) {
        int4 r4 = row4[g];
        int4 c4 = col4[g];
        int rr[4] = {r4.x, r4.y, r4.z, r4.w};
        int cc[4] = {c4.x, c4.y, c4.z, c4.w};
        #pragma unroll
        for (int j = 0; j < 4; ++j) {
            int e = 4 * g + j;
            if (e >= n_edges) break;
            int rl = rr[j] - cbase;
            int cl = cc[j] - cbase;
            bool hr = (unsigned)rl < (unsigned)CHUNK;
            bool hc = (unsigned)cl < (unsigned)CHUNK;
            if (!(hr || hc)) continue;
            float fx, fy, fz, ec;
            edge_math(dij[3 * e], dij[3 * e + 1], dij[3 * e + 2],
                      q[rr[j]], q[cc[j]], gA, fx, fy, fz, ec);
            if (hr) {
                atomicAdd(&acc[4 * rl + 0], fx);
                atomicAdd(&acc[4 * rl + 1], fy);
                atomicAdd(&acc[4 * rl + 2], fz);
                atomicAdd(&acc[4 * rl + 3], ec);
            }
            if (hc) {
                atomicAdd(&acc[4 * cl + 0], -fx);
                atomicAdd(&acc[4 * cl + 1], -fy);
                atomicAdd(&acc[4 * cl + 2], -fz);
            }
        }
    }
    __syncthreads();
    float4* dst = (float4*)partial + (size_t)(c * n_slices + p) * CHUNK;
    const float4* src = (const float4*)acc;
    for (int i = threadIdx.x; i < CHUNK; i += 1024) dst[i] = src[i];
}

__global__ __launch_bounds__(256) void finalize_kernel(
    const float* __restrict__ partial, const int* __restrict__ batch,
    float* __restrict__ energy, float* __restrict__ force,
    int n_atoms, int n_slices)
{
    int i = blockIdx.x * blockDim.x + threadIdx.x;
    float fx = 0.f, fy = 0.f, fz = 0.f, en = 0.f;
    if (i < n_atoms) {
        int c = i >> CHUNK_LOG;
        int l = i & (CHUNK - 1);
        const float4* base = (const float4*)partial + (size_t)c * n_slices * CHUNK + l;
        for (int p = 0; p < n_slices; ++p) {
            float4 v = base[(size_t)p * CHUNK];
            fx += v.x; fy += v.y; fz += v.z; en += v.w;
        }
        force[3 * i + 0] = fx;
        force[3 * i + 1] = fy;
        force[3 * i + 2] = fz;
    }
    int ic = i < n_atoms ? i : (n_atoms - 1);
    int b = batch[ic];
    float v = (i < n_atoms) ? en : 0.0f;
    int b0 = __shfl(b, 0, 64);
    unsigned long long m = __ballot(b == b0);
    if (m == ~0ull) {
        for (int off = 32; off > 0; off >>= 1)
            v += __shfl_down(v, off, 64);
        if ((threadIdx.x & 63) == 0) atomicAdd(&energy[b0], v);
    } else {
        atomicAdd(&energy[b], v);
    }
}

extern "C" void kernel_launch(void* const* d_in, const int* in_sizes, int n_in,
                              void* d_out, int out_size, void* d_ws, size_t ws_size,
                              hipStream_t stream) {
    const float* dij     = (const float*)d_in[0];
    const float* q       = (const float*)d_in[1];
    const float* g_ewald = (const float*)d_in[2];
    const int*   row     = (const int*)d_in[3];
    const int*   col     = (const int*)d_in[4];
    const int*   batch   = (const int*)d_in[5];

    int n_edges = in_sizes[0] / 3;
    int n_atoms = in_sizes[1];

    float* energy = (float*)d_out;               // [256]
    float* force  = (float*)d_out + N_GRAPHS_C;  // [n_atoms*3]

    int nb = (n_atoms + CHUNK - 1) >> CHUNK_LOG;            // 49
    int n4 = n_edges >> 2;

    size_t sz_partial = (size_t)nb * NSLICE * 3 * CHUNK * sizeof(int);  // ~29 MB
    size_t sz_ovf     = (size_t)3 * n_atoms * sizeof(float);
    size_t sz_qg      = (size_t)n_atoms * sizeof(float2);

    // Adaptive tile selection. nb=49 buckets: tile 1024 -> mean 167/run,
    // sigma ~13 -> cap 256 is +7 sigma; tile 2048 -> mean 334, cap 512 = +10.
    // Rare overflow goes through ovf atomics (still correct).
    const int  tile_sel[2]   = {1024, 2048};
    const int  mincap_sel[2] = {224, 416};
    const int  capmax_sel[2] = {256, 512};

    int tile_g = 0, cap = 0, nblkA = 0;
    size_t sz_epart = 0, sz_cnt = 0;
    for (int t = 0; t < 2 && tile_g == 0; ++t) {
        int nba = (n4 + tile_sel[t] - 1) / tile_sel[t];
        size_t se = (size_t)nba * N_GRAPHS_C * sizeof(float);
        size_t sc = (size_t)nba * nb * sizeof(unsigned);
        size_t fixed = ((sz_partial + 255) & ~(size_t)255) +
                       ((se         + 255) & ~(size_t)255) +
                       ((sc         + 255) & ~(size_t)255) +
                       ((sz_ovf     + 255) & ~(size_t)255) +
                       ((sz_qg      + 255) & ~(size_t)255) + 512;
        if ((long long)ws_size > (long long)fixed) {
            long long c = ((long long)ws_size - (long long)fixed) /
                          ((long long)nba * nb * 8);
            c = (c / 32) * 32;
            if (c > capmax_sel[t]) c = capmax_sel[t];
            if (c >= mincap_sel[t]) {
                tile_g = tile_sel[t]; cap = (int)c; nblkA = nba;
                sz_epart = se; sz_cnt = sc;
            }
        }
    }

    bool fast = (nb <= MAXB) && ((n_edges & 3) == 0) && (tile_g > 0);

    if (fast) {
        char* ws = (char*)d_ws;
        size_t off = 0;
        uint2*    records  = (uint2*)(ws + off);
        off += (size_t)nblkA * nb * cap * 8;   off = (off + 255) & ~(size_t)255;
        int*      partial  = (int*)(ws + off);
        off += sz_partial;                     off = (off + 255) & ~(size_t)255;
        float*    e_part   = (float*)(ws + off);
        off += sz_epart;                       off = (off + 255) & ~(size_t)255;
        unsigned* cnt_tab  = (unsigned*)(ws + off);
        off += sz_cnt;                         off = (off + 255) & ~(size_t)255;
        float*    ovf      = (float*)(ws + off);
        off += sz_ovf;                         off = (off + 255) & ~(size_t)255;
        float2*   qg       = (float2*)(ws + off);

        prep_qg<<<(n_atoms + 255) / 256, 256, 0, stream>>>(q, batch, qg, ovf, n_atoms);

        passA<<<nblkA, TPA, 0, stream>>>(
            dij, qg, g_ewald, row, col,
            records, cap, cnt_tab, e_part, ovf, n_edges, nb, tile_g);

        passB<<<nb * NSLICE, TPBB, 0, stream>>>(
            records, cap, cnt_tab, partial, nblkA, nb, NSLICE);

        int nfblk = (n_atoms + 255) / 256;
        fin_force<<<nfblk + N_GRAPHS_C / 4, 256, 0, stream>>>(
            partial, ovf, e_part, force, energy, n_atoms, NSLICE, nblkA, nfblk);
    } else {
        size_t need_chunk = (size_t)nb * NSLICE_FB * CHUNK * 4 * sizeof(float);
        if (ws_size >= need_chunk) {
            hipMemsetAsync(d_out, 0, N_GRAPHS_C * sizeof(float), stream);
            chunk_kernel<<<nb * NSLICE_FB, 1024, 0, stream>>>(
                dij, q, g_ewald, row, col, (float*)d_ws, n_edges, nb, NSLICE_FB);
            finalize_kernel<<<(n_atoms + 255) / 256, 256, 0, stream>>>(
                (const float*)d_ws, batch, energy, force, n_atoms, NSLICE_FB);
        }
    }
}

// Round 6
// 360.248 us; speedup vs baseline: 1.3718x; 1.1021x over previous
//
#include <hip/hip_runtime.h>
#include <hip/hip_fp16.h>

#define N_GRAPHS_C 256
#define CHUNK_LOG 12
#define CHUNK (1 << CHUNK_LOG)   // 4096 atoms per bucket
#define MAXB 64
#define NSLICE 12                // passB slices per bucket (48 KB LDS -> 3 blocks/CU)
#define NSLICE_FB 10
#define TPA 256
#define TPBB 512
#define SD 64                    // LDS staging depth per bucket (mean 42/phase, +3.5 sigma)
#define FP_SCALE 1024.0f
#define FP_INV   (1.0f / 1024.0f)

// ---------------- shared per-edge math ----------------
// Units: Angstrom, electron charge, eV (avoids fp32 denormals from the
// reference's SI-unit charges; algebraically identical).
__device__ __forceinline__ void edge_math(
    float dx, float dy, float dz, float qr, float qc, float gA,
    float& fx, float& fy, float& fz, float& ecoul)
{
    const float KEV = (float)(8987551792.3 * 1.602176634e-9); // 14.3996 eV*A/e^2
    float r2 = dx * dx + dy * dy + dz * dz;
    float inv_r = rsqrtf(r2);
    float rA = r2 * inv_r;

    float pref = KEV * qr * qc * inv_r;

    float damp = 1.0f;
    if (rA < 2.2f)
        damp = __expf(-18.7f * (2.2f - rA) * (1.0f / 2.2f));

    float grij = gA * rA;
    float expm2 = __expf(-grij * grij);
    float t = 1.0f / (1.0f + 0.3275911f * grij);
    float erfc = t * (0.254829592f +
                 t * (-0.284496736f +
                 t * (1.421413741f +
                 t * (-1.453152027f +
                 t * 1.061405429f)))) * expm2;

    ecoul = pref * (0.5f * damp + (erfc - 1.0f));
    float S = damp + erfc + 2.0f * grij * expm2 - 1.0f;
    float fs = pref * S * (inv_r * inv_r);
    fx = dx * fs; fy = dy * fs; fz = dz * fs;
}

__device__ __forceinline__ uint2 pack_rec(float fx, float fy, float fz, unsigned lid)
{
    uint2 u;
    u.x = __builtin_bit_cast(unsigned, __floats2half2_rn(fx, fy));
    u.y = (__builtin_bit_cast(unsigned, __floats2half2_rn(fz, 0.0f)) & 0xFFFFu) |
          (lid << 16);
    return u;
}

// passB record accumulate: f16 record -> i32 fixed-point (scale 2^10) into
// three full-width planes via native integer LDS atomics (ds_add_u32).
__device__ __forceinline__ void acc_rec(int* acc, unsigned w0, unsigned w1)
{
    float2 xy = __half22float2(__builtin_bit_cast(__half2, w0));
    float fz = __half2float(__builtin_bit_cast(__half2, w1).x);   // low half
    unsigned idx = w1 >> 16;
    atomicAdd(&acc[idx],             __float2int_rn(xy.x * FP_SCALE));
    atomicAdd(&acc[CHUNK + idx],     __float2int_rn(xy.y * FP_SCALE));
    atomicAdd(&acc[2 * CHUNK + idx], __float2int_rn(fz   * FP_SCALE));
}

// prep: fuse q[] and batch[] into one 8 B table so passA does 2 scattered
// gathers per edge instead of 3. Also zeroes ovf[] (replaces a memset launch).
__global__ __launch_bounds__(256) void prep_qg(
    const float* __restrict__ q, const int* __restrict__ batch,
    float2* __restrict__ qg, float* __restrict__ ovf, int n_atoms)
{
    int i = blockIdx.x * 256 + threadIdx.x;
    if (i < n_atoms) {
        qg[i] = make_float2(q[i], __int_as_float(batch[i]));
        ovf[3 * i + 0] = 0.f;
        ovf[3 * i + 1] = 0.f;
        ovf[3 * i + 2] = 0.f;
    }
}

// ================= fast path =================
// passA with LDS-staged coalesced record flush. Phased: each phase computes
// TPA*4 edges, appending records into per-bucket LDS stages (rank via LDS
// atomic; stage overflow -> full-precision ovf atomics, ~1e-5 of records);
// then a wave-cooperative flush copies each bucket's staged run to its global
// records region as contiguous coalesced stores (one block-counter
// reservation per bucket per phase). This removes the 2 scattered 8 B global
// stores/edge that r4/r5 isolated as passA's binding resource; only the 2
// qg gathers remain scattered. Next-phase indices+gathers are issued before
// the flush barrier so their latency hides under the flush.
__global__ __launch_bounds__(TPA) void passA(
    const float* __restrict__ dij, const float2* __restrict__ qg,
    const float* __restrict__ g_ewald,
    const int* __restrict__ row, const int* __restrict__ col,
    uint2* __restrict__ records, int cap,
    unsigned* __restrict__ cnt_table,
    float* __restrict__ e_part,
    float* __restrict__ ovf,
    int n_edges, int nb, int tile_g)
{
    __shared__ uint2    stage[MAXB][SD];        // 32 KB
    __shared__ unsigned scnt[MAXB];             // per-phase stage counts
    __shared__ unsigned cnt[MAXB];              // per-block reserved slots
    __shared__ float    e_graph[4 * N_GRAPHS_C];

    int tid  = threadIdx.x;
    int wid  = tid >> 6;
    int lane = tid & 63;
    if (tid < MAXB) { scnt[tid] = 0u; cnt[tid] = 0u; }
    for (int i = tid; i < 4 * N_GRAPHS_C; i += TPA) e_graph[i] = 0.f;
    __syncthreads();

    float* e_my = &e_graph[wid * N_GRAPHS_C];

    int n4 = n_edges >> 2;
    int gbase = blockIdx.x * tile_g;
    int g1 = min(gbase + tile_g, n4);
    int nph = tile_g / TPA;

    const int4* row4 = (const int4*)row;
    const int4* col4 = (const int4*)col;
    const float4* dij4 = (const float4*)dij;

    const float gA = g_ewald[0] * 1e-10f;    // 1/m -> 1/Angstrom
    size_t blk_base = (size_t)blockIdx.x * nb * cap;

    // prologue: indices + gathers for phase 0
    int4 r_cur = make_int4(0, 0, 0, 0), c_cur = make_int4(0, 0, 0, 0);
    float2 vr_cur[4], vc_cur[4];
    {
        int g = gbase + tid;
        if (g < g1) { r_cur = row4[g]; c_cur = col4[g]; }
        vr_cur[0] = qg[r_cur.x]; vc_cur[0] = qg[c_cur.x];
        vr_cur[1] = qg[r_cur.y]; vc_cur[1] = qg[c_cur.y];
        vr_cur[2] = qg[r_cur.z]; vc_cur[2] = qg[c_cur.z];
        vr_cur[3] = qg[r_cur.w]; vc_cur[3] = qg[c_cur.w];
    }

    for (int p = 0; p < nph; ++p) {
        int g = gbase + p * TPA + tid;

        // next phase's indices (issued early; qg[0] dummies past the end)
        int4 r_nxt = make_int4(0, 0, 0, 0), c_nxt = make_int4(0, 0, 0, 0);
        if (p + 1 < nph && g + TPA < g1) {
            r_nxt = row4[g + TPA]; c_nxt = col4[g + TPA];
        }

        if (g < g1) {
            float4 d0 = dij4[3 * g + 0];
            float4 d1 = dij4[3 * g + 1];
            float4 d2 = dij4[3 * g + 2];
            float ex[4] = {d0.x, d0.w, d1.z, d2.y};
            float ey[4] = {d0.y, d1.x, d1.w, d2.z};
            float ez[4] = {d0.z, d1.y, d2.x, d2.w};
            int rr[4] = {r_cur.x, r_cur.y, r_cur.z, r_cur.w};
            int cc[4] = {c_cur.x, c_cur.y, c_cur.z, c_cur.w};

            #pragma unroll
            for (int j = 0; j < 4; ++j) {
                int r = rr[j], c = cc[j];
                float fx, fy, fz, ec;
                edge_math(ex[j], ey[j], ez[j], vr_cur[j].x, vc_cur[j].x, gA,
                          fx, fy, fz, ec);

                atomicAdd(&e_my[__float_as_int(vr_cur[j].y)], ec);

                int br = r >> CHUNK_LOG, bc = c >> CHUNK_LOG;
                unsigned pr = atomicAdd(&scnt[br], 1u);
                unsigned pc = atomicAdd(&scnt[bc], 1u);
                if (pr < SD)
                    stage[br][pr] = pack_rec(fx, fy, fz, (unsigned)(r & (CHUNK - 1)));
                else {
                    atomicAdd(&ovf[3 * r + 0], fx);
                    atomicAdd(&ovf[3 * r + 1], fy);
                    atomicAdd(&ovf[3 * r + 2], fz);
                }
                if (pc < SD)
                    stage[bc][pc] = pack_rec(-fx, -fy, -fz, (unsigned)(c & (CHUNK - 1)));
                else {
                    atomicAdd(&ovf[3 * c + 0], -fx);
                    atomicAdd(&ovf[3 * c + 1], -fy);
                    atomicAdd(&ovf[3 * c + 2], -fz);
                }
            }
        }

        // issue next phase's gathers now: latency hides under the flush
        float2 vr_n[4], vc_n[4];
        vr_n[0] = qg[r_nxt.x]; vc_n[0] = qg[c_nxt.x];
        vr_n[1] = qg[r_nxt.y]; vc_n[1] = qg[c_nxt.y];
        vr_n[2] = qg[r_nxt.z]; vc_n[2] = qg[c_nxt.z];
        vr_n[3] = qg[r_nxt.w]; vc_n[3] = qg[c_nxt.w];

        __syncthreads();

        // wave-cooperative flush: wave handles buckets wid, wid+4, ...
        for (int b = wid; b < nb; b += TPA / 64) {
            unsigned m = min(scnt[b], (unsigned)SD);
            unsigned base = 0;
            if (lane == 0) base = atomicAdd(&cnt[b], m);
            base = (unsigned)__shfl((int)base, 0, 64);
            for (unsigned i = lane; i < m; i += 64) {
                uint2 rv = stage[b][i];
                unsigned slot = base + i;
                if (slot < (unsigned)cap) {
                    records[blk_base + (size_t)b * cap + slot] = rv;
                } else {
                    float2 xy = __half22float2(__builtin_bit_cast(__half2, rv.x));
                    float fzv = __half2float(__builtin_bit_cast(__half2, rv.y).x);
                    int atom = (b << CHUNK_LOG) + (int)(rv.y >> 16);
                    atomicAdd(&ovf[3 * atom + 0], xy.x);
                    atomicAdd(&ovf[3 * atom + 1], xy.y);
                    atomicAdd(&ovf[3 * atom + 2], fzv);
                }
            }
            if (lane == 0) scnt[b] = 0u;
        }
        __syncthreads();

        r_cur = r_nxt; c_cur = c_nxt;
        #pragma unroll
        for (int j = 0; j < 4; ++j) { vr_cur[j] = vr_n[j]; vc_cur[j] = vc_n[j]; }
    }

    if (tid < nb) cnt_table[(size_t)blockIdx.x * nb + tid] = min(cnt[tid], (unsigned)cap);
    for (int g2 = tid; g2 < N_GRAPHS_C; g2 += TPA)
        e_part[(size_t)blockIdx.x * N_GRAPHS_C + g2] =
            e_graph[g2] + e_graph[N_GRAPHS_C + g2] +
            e_graph[2 * N_GRAPHS_C + g2] + e_graph[3 * N_GRAPHS_C + g2];
}

// passB: block (b,s); each wave takes whole runs. Accumulates into three
// full-width i32 fixed-point planes (48 KB) via native ds_add_u32 -- exact,
// deterministic, full-rate (r4: pk_f16 slow path was the passB wall).
__global__ __launch_bounds__(TPBB) void passB(
    const uint2* __restrict__ records, int cap,
    const unsigned* __restrict__ cnt_table,
    int* __restrict__ partial, int nblkA, int nb, int nslice)
{
    __shared__ int acc[3 * CHUNK];

    int b = blockIdx.x / nslice;
    int s = blockIdx.x % nslice;
    int k0 = (int)((long long)s * nblkA / nslice);
    int k1 = (int)((long long)(s + 1) * nblkA / nslice);

    for (int i = threadIdx.x; i < 3 * CHUNK; i += TPBB) acc[i] = 0;
    __syncthreads();

    int wid  = threadIdx.x >> 6;
    int lane = threadIdx.x & 63;

    for (int k = k0 + wid; k < k1; k += TPBB / 64) {
        unsigned n = cnt_table[(size_t)k * nb + b];       // wave-uniform
        const uint2* rec = records + ((size_t)k * nb + b) * cap;
        const uint4* rec4 = (const uint4*)rec;            // cap%32==0 -> 256B aligned
        unsigned nh = n >> 1;
        for (unsigned i = lane; i < nh; i += 64) {
            uint4 v = rec4[i];
            acc_rec(acc, v.x, v.y);
            acc_rec(acc, v.z, v.w);
        }
        if ((n & 1u) && lane == 0) {                      // odd tail record
            uint2 t = rec[n - 1];
            acc_rec(acc, t.x, t.y);
        }
    }
    __syncthreads();

    int* dst = partial + (size_t)blockIdx.x * 3 * CHUNK;
    for (int i = threadIdx.x; i < 3 * CHUNK; i += TPBB) dst[i] = acc[i];
}

// fin_force: blocks [0,nfblk) reduce force partials (exact integer sums);
// blocks [nfblk, nfblk+64) do the energy reduction (one wave per graph).
__global__ __launch_bounds__(256) void fin_force(
    const int* __restrict__ partial, const float* __restrict__ ovf,
    const float* __restrict__ e_part,
    float* __restrict__ force, float* __restrict__ energy,
    int n_atoms, int nslice, int nblkA, int nfblk)
{
    if ((int)blockIdx.x >= nfblk) {
        int g = (blockIdx.x - nfblk) * 4 + (threadIdx.x >> 6);   // graph per wave
        int lane = threadIdx.x & 63;
        float s = 0.f;
        for (int k = lane; k < nblkA; k += 64)
            s += e_part[(size_t)k * N_GRAPHS_C + g];
        for (int off = 32; off > 0; off >>= 1) s += __shfl_down(s, off, 64);
        if (lane == 0) energy[g] = s;
        return;
    }
    int a = blockIdx.x * 256 + threadIdx.x;
    if (a >= n_atoms) return;
    int b = a >> CHUNK_LOG, l = a & (CHUNK - 1);
    long long sx = 0, sy = 0, sz = 0;
    const int* p = partial + (size_t)b * nslice * 3 * CHUNK + l;
    for (int s = 0; s < nslice; ++s) {
        const int* ps = p + (size_t)s * 3 * CHUNK;
        sx += ps[0]; sy += ps[CHUNK]; sz += ps[2 * CHUNK];
    }
    force[3 * a + 0] = ovf[3 * a + 0] + (float)sx * FP_INV;
    force[3 * a + 1] = ovf[3 * a + 1] + (float)sy * FP_INV;
    force[3 * a + 2] = ovf[3 * a + 2] + (float)sz * FP_INV;
}

// ================= fallback: chunk-scan path =================
__global__ __launch_bounds__(1024) void chunk_kernel(
    const float* __restrict__ dij, const float* __restrict__ q,
    const float* __restrict__ g_ewald,
    const int* __restrict__ row, const int* __restrict__ col,
    float* __restrict__ partial, int n_edges, int n_chunks, int n_slices)
{
    __shared__ float acc[CHUNK * 4];
    int c = blockIdx.x % n_chunks;
    int p = blockIdx.x / n_chunks;
    int cbase = c << CHUNK_LOG;
    for (int i = threadIdx.x; i < CHUNK * 4; i += 1024) acc[i] = 0.f;
    __syncthreads();
    const float gA = g_ewald[0] * 1e-10f;
    int n4 = (n_edges + 3) >> 2;
    int g0 = (int)((long long)p * n4 / n_slices);
    int g1 = (int)((long long)(p + 1) * n4 / n_slices);
    const int4* row4 = (const int4*)row;
    const int4* col4 = (const int4*)col;
    for (int g = g0 + threadIdx.x; g < g1; g += 1024) {
        int4 r4 = row4[g];
        int4 c4 = col4[g];
        int rr[4] = {r4.x, r4.y, r4.z, r4.w};
        int cc[4] = {c4.x, c4.y, c4.z, c4.w};
        #pragma unroll
        for (int j = 0; j < 4; ++j) {
            int e = 4 * g + j;
            if (e >= n_edges) break;
            int rl = rr[j] - cbase;
            int cl = cc[j] - cbase;
            bool hr = (unsigned)rl < (unsigned)CHUNK;
            bool hc = (unsigned)cl < (unsigned)CHUNK;
            if (!(hr || hc)) continue;
            float fx, fy, fz, ec;
            edge_math(dij[3 * e], dij[3 * e + 1], dij[3 * e + 2],
                      q[rr[j]], q[cc[j]], gA, fx, fy, fz, ec);
            if (hr) {
                atomicAdd(&acc[4 * rl + 0], fx);
                atomicAdd(&acc[4 * rl + 1], fy);
                atomicAdd(&acc[4 * rl + 2], fz);
                atomicAdd(&acc[4 * rl + 3], ec);
            }
            if (hc) {
                atomicAdd(&acc[4 * cl + 0], -fx);
                atomicAdd(&acc[4 * cl + 1], -fy);
                atomicAdd(&acc[4 * cl + 2], -fz);
            }
        }
    }
    __syncthreads();
    float4* dst = (float4*)partial + (size_t)(c * n_slices + p) * CHUNK;
    const float4* src = (const float4*)acc;
    for (int i = threadIdx.x; i < CHUNK; i += 1024) dst[i] = src[i];
}

__global__ __launch_bounds__(256) void finalize_kernel(
    const float* __restrict__ partial, const int* __restrict__ batch,
    float* __restrict__ energy, float* __restrict__ force,
    int n_atoms, int n_slices)
{
    int i = blockIdx.x * blockDim.x + threadIdx.x;
    float fx = 0.f, fy = 0.f, fz = 0.f, en = 0.f;
    if (i < n_atoms) {
        int c = i >> CHUNK_LOG;
        int l = i & (CHUNK - 1);
        const float4* base = (const float4*)partial + (size_t)c * n_slices * CHUNK + l;
        for (int p = 0; p < n_slices; ++p) {
            float4 v = base[(size_t)p * CHUNK];
            fx += v.x; fy += v.y; fz += v.z; en += v.w;
        }
        force[3 * i + 0] = fx;
        force[3 * i + 1] = fy;
        force[3 * i + 2] = fz;
    }
    int ic = i < n_atoms ? i : (n_atoms - 1);
    int b = batch[ic];
    float v = (i < n_atoms) ? en : 0.0f;
    int b0 = __shfl(b, 0, 64);
    unsigned long long m = __ballot(b == b0);
    if (m == ~0ull) {
        for (int off = 32; off > 0; off >>= 1)
            v += __shfl_down(v, off, 64);
        if ((threadIdx.x & 63) == 0) atomicAdd(&energy[b0], v);
    } else {
        atomicAdd(&energy[b], v);
    }
}

extern "C" void kernel_launch(void* const* d_in, const int* in_sizes, int n_in,
                              void* d_out, int out_size, void* d_ws, size_t ws_size,
                              hipStream_t stream) {
    const float* dij     = (const float*)d_in[0];
    const float* q       = (const float*)d_in[1];
    const float* g_ewald = (const float*)d_in[2];
    const int*   row     = (const int*)d_in[3];
    const int*   col     = (const int*)d_in[4];
    const int*   batch   = (const int*)d_in[5];

    int n_edges = in_sizes[0] / 3;
    int n_atoms = in_sizes[1];

    float* energy = (float*)d_out;               // [256]
    float* force  = (float*)d_out + N_GRAPHS_C;  // [n_atoms*3]

    int nb = (n_atoms + CHUNK - 1) >> CHUNK_LOG;            // 49
    int n4 = n_edges >> 2;

    size_t sz_partial = (size_t)nb * NSLICE * 3 * CHUNK * sizeof(int);  // ~29 MB
    size_t sz_ovf     = (size_t)3 * n_atoms * sizeof(float);
    size_t sz_qg      = (size_t)n_atoms * sizeof(float2);

    // Adaptive tile selection. nb=49 buckets: tile 1024 -> mean 167/run,
    // sigma ~13 -> cap 256 is +7 sigma; tile 2048 -> mean 334, cap 512 = +10.
    // Rare overflow goes through ovf atomics (still correct).
    const int  tile_sel[2]   = {1024, 2048};
    const int  mincap_sel[2] = {224, 416};
    const int  capmax_sel[2] = {256, 512};

    int tile_g = 0, cap = 0, nblkA = 0;
    size_t sz_epart = 0, sz_cnt = 0;
    for (int t = 0; t < 2 && tile_g == 0; ++t) {
        int nba = (n4 + tile_sel[t] - 1) / tile_sel[t];
        size_t se = (size_t)nba * N_GRAPHS_C * sizeof(float);
        size_t sc = (size_t)nba * nb * sizeof(unsigned);
        size_t fixed = ((sz_partial + 255) & ~(size_t)255) +
                       ((se         + 255) & ~(size_t)255) +
                       ((sc         + 255) & ~(size_t)255) +
                       ((sz_ovf     + 255) & ~(size_t)255) +
                       ((sz_qg      + 255) & ~(size_t)255) + 512;
        if ((long long)ws_size > (long long)fixed) {
            long long c = ((long long)ws_size - (long long)fixed) /
                          ((long long)nba * nb * 8);
            c = (c / 32) * 32;
            if (c > capmax_sel[t]) c = capmax_sel[t];
            if (c >= mincap_sel[t]) {
                tile_g = tile_sel[t]; cap = (int)c; nblkA = nba;
                sz_epart = se; sz_cnt = sc;
            }
        }
    }

    bool fast = (nb <= MAXB) && ((n_edges & 3) == 0) && (tile_g > 0) &&
                ((tile_g % TPA) == 0);

    if (fast) {
        char* ws = (char*)d_ws;
        size_t off = 0;
        uint2*    records  = (uint2*)(ws + off);
        off += (size_t)nblkA * nb * cap * 8;   off = (off + 255) & ~(size_t)255;
        int*      partial  = (int*)(ws + off);
        off += sz_partial;                     off = (off + 255) & ~(size_t)255;
        float*    e_part   = (float*)(ws + off);
        off += sz_epart;                       off = (off + 255) & ~(size_t)255;
        unsigned* cnt_tab  = (unsigned*)(ws + off);
        off += sz_cnt;                         off = (off + 255) & ~(size_t)255;
        float*    ovf      = (float*)(ws + off);
        off += sz_ovf;                         off = (off + 255) & ~(size_t)255;
        float2*   qg       = (float2*)(ws + off);

        prep_qg<<<(n_atoms + 255) / 256, 256, 0, stream>>>(q, batch, qg, ovf, n_atoms);

        passA<<<nblkA, TPA, 0, stream>>>(
            dij, qg, g_ewald, row, col,
            records, cap, cnt_tab, e_part, ovf, n_edges, nb, tile_g);

        passB<<<nb * NSLICE, TPBB, 0, stream>>>(
            records, cap, cnt_tab, partial, nblkA, nb, NSLICE);

        int nfblk = (n_atoms + 255) / 256;
        fin_force<<<nfblk + N_GRAPHS_C / 4, 256, 0, stream>>>(
            partial, ovf, e_part, force, energy, n_atoms, NSLICE, nblkA, nfblk);
    } else {
        size_t need_chunk = (size_t)nb * NSLICE_FB * CHUNK * 4 * sizeof(float);
        if (ws_size >= need_chunk) {
            hipMemsetAsync(d_out, 0, N_GRAPHS_C * sizeof(float), stream);
            chunk_kernel<<<nb * NSLICE_FB, 1024, 0, stream>>>(
                dij, q, g_ewald, row, col, (float*)d_ws, n_edges, nb, NSLICE_FB);
            finalize_kernel<<<(n_atoms + 255) / 256, 256, 0, stream>>>(
                (const float*)d_ws, batch, energy, force, n_atoms, NSLICE_FB);
        }
    }
}

// Round 7
// 352.273 us; speedup vs baseline: 1.4029x; 1.0226x over previous
//
#include <hip/hip_runtime.h>
#include <hip/hip_fp16.h>

#define N_GRAPHS_C 256
#define CHUNK_LOG 12
#define CHUNK (1 << CHUNK_LOG)   // 4096 atoms per bucket
#define MAXB 64
#define NSLICE 16                // passB slices per bucket (48 KB LDS -> 3 blocks/CU)
#define NSLICE_FB 10
#define TPA 256
#define TPBB 512
#define SD 64                    // LDS staging depth per bucket (mean 42/phase, +3.5 sigma)
#define FP_SCALE 1024.0f
#define FP_INV   (1.0f / 1024.0f)

// ---------------- shared per-edge math ----------------
// Units: Angstrom, electron charge, eV (avoids fp32 denormals from the
// reference's SI-unit charges; algebraically identical).
__device__ __forceinline__ void edge_math(
    float dx, float dy, float dz, float qr, float qc, float gA,
    float& fx, float& fy, float& fz, float& ecoul)
{
    const float KEV = (float)(8987551792.3 * 1.602176634e-9); // 14.3996 eV*A/e^2
    float r2 = dx * dx + dy * dy + dz * dz;
    float inv_r = rsqrtf(r2);
    float rA = r2 * inv_r;

    float pref = KEV * qr * qc * inv_r;

    float damp = 1.0f;
    if (rA < 2.2f)
        damp = __expf(-18.7f * (2.2f - rA) * (1.0f / 2.2f));

    float grij = gA * rA;
    float expm2 = __expf(-grij * grij);
    float t = 1.0f / (1.0f + 0.3275911f * grij);
    float erfc = t * (0.254829592f +
                 t * (-0.284496736f +
                 t * (1.421413741f +
                 t * (-1.453152027f +
                 t * 1.061405429f)))) * expm2;

    ecoul = pref * (0.5f * damp + (erfc - 1.0f));
    float S = damp + erfc + 2.0f * grij * expm2 - 1.0f;
    float fs = pref * S * (inv_r * inv_r);
    fx = dx * fs; fy = dy * fs; fz = dz * fs;
}

__device__ __forceinline__ uint2 pack_rec(float fx, float fy, float fz, unsigned lid)
{
    uint2 u;
    u.x = __builtin_bit_cast(unsigned, __floats2half2_rn(fx, fy));
    u.y = (__builtin_bit_cast(unsigned, __floats2half2_rn(fz, 0.0f)) & 0xFFFFu) |
          (lid << 16);
    return u;
}

// passB record accumulate: f16 record -> i32 fixed-point (scale 2^10) into
// three full-width planes via native integer LDS atomics (ds_add_u32).
__device__ __forceinline__ void acc_rec(int* acc, unsigned w0, unsigned w1)
{
    float2 xy = __half22float2(__builtin_bit_cast(__half2, w0));
    float fz = __half2float(__builtin_bit_cast(__half2, w1).x);   // low half
    unsigned idx = w1 >> 16;
    atomicAdd(&acc[idx],             __float2int_rn(xy.x * FP_SCALE));
    atomicAdd(&acc[CHUNK + idx],     __float2int_rn(xy.y * FP_SCALE));
    atomicAdd(&acc[2 * CHUNK + idx], __float2int_rn(fz   * FP_SCALE));
}

// prep: fuse q[] and batch[] into one 8 B table so passA does 2 scattered
// gathers per edge instead of 3. Also zeroes ovf[] (replaces a memset launch).
__global__ __launch_bounds__(256) void prep_qg(
    const float* __restrict__ q, const int* __restrict__ batch,
    float2* __restrict__ qg, float* __restrict__ ovf, int n_atoms)
{
    int i = blockIdx.x * 256 + threadIdx.x;
    if (i < n_atoms) {
        qg[i] = make_float2(q[i], __int_as_float(batch[i]));
        ovf[3 * i + 0] = 0.f;
        ovf[3 * i + 1] = 0.f;
        ovf[3 * i + 2] = 0.f;
    }
}

// ================= fast path =================
// passA with LDS-staged coalesced record flush (r6: -38us vs scattered
// stores). Stage rows padded to SD+1 (130 dwords = 2 mod 32 banks): unpadded,
// same-rank appends into different buckets all aliased to one bank pair
// (6.3M conflict cycles in r6).
__global__ __launch_bounds__(TPA) void passA(
    const float* __restrict__ dij, const float2* __restrict__ qg,
    const float* __restrict__ g_ewald,
    const int* __restrict__ row, const int* __restrict__ col,
    uint2* __restrict__ records, int cap,
    unsigned* __restrict__ cnt_table,
    float* __restrict__ e_part,
    float* __restrict__ ovf,
    int n_edges, int nb, int tile_g)
{
    __shared__ uint2    stage[MAXB][SD + 1];    // +1 pad: bank de-aliasing
    __shared__ unsigned scnt[MAXB];             // per-phase stage counts
    __shared__ unsigned cnt[MAXB];              // per-block reserved slots
    __shared__ float    e_graph[4 * N_GRAPHS_C];

    int tid  = threadIdx.x;
    int wid  = tid >> 6;
    int lane = tid & 63;
    if (tid < MAXB) { scnt[tid] = 0u; cnt[tid] = 0u; }
    for (int i = tid; i < 4 * N_GRAPHS_C; i += TPA) e_graph[i] = 0.f;
    __syncthreads();

    float* e_my = &e_graph[wid * N_GRAPHS_C];

    int n4 = n_edges >> 2;
    int gbase = blockIdx.x * tile_g;
    int g1 = min(gbase + tile_g, n4);
    int nph = tile_g / TPA;

    const int4* row4 = (const int4*)row;
    const int4* col4 = (const int4*)col;
    const float4* dij4 = (const float4*)dij;

    const float gA = g_ewald[0] * 1e-10f;    // 1/m -> 1/Angstrom
    size_t blk_base = (size_t)blockIdx.x * nb * cap;

    // prologue: indices + gathers for phase 0
    int4 r_cur = make_int4(0, 0, 0, 0), c_cur = make_int4(0, 0, 0, 0);
    float2 vr_cur[4], vc_cur[4];
    {
        int g = gbase + tid;
        if (g < g1) { r_cur = row4[g]; c_cur = col4[g]; }
        vr_cur[0] = qg[r_cur.x]; vc_cur[0] = qg[c_cur.x];
        vr_cur[1] = qg[r_cur.y]; vc_cur[1] = qg[c_cur.y];
        vr_cur[2] = qg[r_cur.z]; vc_cur[2] = qg[c_cur.z];
        vr_cur[3] = qg[r_cur.w]; vc_cur[3] = qg[c_cur.w];
    }

    for (int p = 0; p < nph; ++p) {
        int g = gbase + p * TPA + tid;

        // next phase's indices (issued early; qg[0] dummies past the end)
        int4 r_nxt = make_int4(0, 0, 0, 0), c_nxt = make_int4(0, 0, 0, 0);
        if (p + 1 < nph && g + TPA < g1) {
            r_nxt = row4[g + TPA]; c_nxt = col4[g + TPA];
        }

        if (g < g1) {
            float4 d0 = dij4[3 * g + 0];
            float4 d1 = dij4[3 * g + 1];
            float4 d2 = dij4[3 * g + 2];
            float ex[4] = {d0.x, d0.w, d1.z, d2.y};
            float ey[4] = {d0.y, d1.x, d1.w, d2.z};
            float ez[4] = {d0.z, d1.y, d2.x, d2.w};
            int rr[4] = {r_cur.x, r_cur.y, r_cur.z, r_cur.w};
            int cc[4] = {c_cur.x, c_cur.y, c_cur.z, c_cur.w};

            #pragma unroll
            for (int j = 0; j < 4; ++j) {
                int r = rr[j], c = cc[j];
                float fx, fy, fz, ec;
                edge_math(ex[j], ey[j], ez[j], vr_cur[j].x, vc_cur[j].x, gA,
                          fx, fy, fz, ec);

                atomicAdd(&e_my[__float_as_int(vr_cur[j].y)], ec);

                int br = r >> CHUNK_LOG, bc = c >> CHUNK_LOG;
                unsigned pr = atomicAdd(&scnt[br], 1u);
                unsigned pc = atomicAdd(&scnt[bc], 1u);
                if (pr < SD)
                    stage[br][pr] = pack_rec(fx, fy, fz, (unsigned)(r & (CHUNK - 1)));
                else {
                    atomicAdd(&ovf[3 * r + 0], fx);
                    atomicAdd(&ovf[3 * r + 1], fy);
                    atomicAdd(&ovf[3 * r + 2], fz);
                }
                if (pc < SD)
                    stage[bc][pc] = pack_rec(-fx, -fy, -fz, (unsigned)(c & (CHUNK - 1)));
                else {
                    atomicAdd(&ovf[3 * c + 0], -fx);
                    atomicAdd(&ovf[3 * c + 1], -fy);
                    atomicAdd(&ovf[3 * c + 2], -fz);
                }
            }
        }

        // issue next phase's gathers now: latency hides under the flush
        float2 vr_n[4], vc_n[4];
        vr_n[0] = qg[r_nxt.x]; vc_n[0] = qg[c_nxt.x];
        vr_n[1] = qg[r_nxt.y]; vc_n[1] = qg[c_nxt.y];
        vr_n[2] = qg[r_nxt.z]; vc_n[2] = qg[c_nxt.z];
        vr_n[3] = qg[r_nxt.w]; vc_n[3] = qg[c_nxt.w];

        __syncthreads();

        // wave-cooperative flush: wave handles buckets wid, wid+4, ...
        for (int b = wid; b < nb; b += TPA / 64) {
            unsigned m = min(scnt[b], (unsigned)SD);
            unsigned base = 0;
            if (lane == 0) base = atomicAdd(&cnt[b], m);
            base = (unsigned)__shfl((int)base, 0, 64);
            for (unsigned i = lane; i < m; i += 64) {
                uint2 rv = stage[b][i];
                unsigned slot = base + i;
                if (slot < (unsigned)cap) {
                    records[blk_base + (size_t)b * cap + slot] = rv;
                } else {
                    float2 xy = __half22float2(__builtin_bit_cast(__half2, rv.x));
                    float fzv = __half2float(__builtin_bit_cast(__half2, rv.y).x);
                    int atom = (b << CHUNK_LOG) + (int)(rv.y >> 16);
                    atomicAdd(&ovf[3 * atom + 0], xy.x);
                    atomicAdd(&ovf[3 * atom + 1], xy.y);
                    atomicAdd(&ovf[3 * atom + 2], fzv);
                }
            }
            if (lane == 0) scnt[b] = 0u;
        }
        __syncthreads();

        r_cur = r_nxt; c_cur = c_nxt;
        #pragma unroll
        for (int j = 0; j < 4; ++j) { vr_cur[j] = vr_n[j]; vc_cur[j] = vc_n[j]; }
    }

    if (tid < nb) cnt_table[(size_t)blockIdx.x * nb + tid] = min(cnt[tid], (unsigned)cap);
    for (int g2 = tid; g2 < N_GRAPHS_C; g2 += TPA)
        e_part[(size_t)blockIdx.x * N_GRAPHS_C + g2] =
            e_graph[g2] + e_graph[N_GRAPHS_C + g2] +
            e_graph[2 * N_GRAPHS_C + g2] + e_graph[3 * N_GRAPHS_C + g2];
}

// passB: block (b,s). Runs are short (~167 records = <=2 uint4 iters/wave),
// so depth-1 execution is all cold-start latency. Each wave processes FOUR
// runs concurrently (4 independent cnt loads, 4 independent uint4 loads in
// flight) feeding exec-masked native-i32 LDS accumulates. r3's identical MLP
// transform was null because pk_f16 DS was the wall; r4 removed that wall.
__global__ __launch_bounds__(TPBB) void passB(
    const uint2* __restrict__ records, int cap,
    const unsigned* __restrict__ cnt_table,
    int* __restrict__ partial, int nblkA, int nb, int nslice)
{
    __shared__ int acc[3 * CHUNK];

    int b = blockIdx.x / nslice;
    int s = blockIdx.x % nslice;
    int k0 = (int)((long long)s * nblkA / nslice);
    int k1 = (int)((long long)(s + 1) * nblkA / nslice);

    for (int i = threadIdx.x; i < 3 * CHUNK; i += TPBB) acc[i] = 0;
    __syncthreads();

    int wid  = threadIdx.x >> 6;
    int lane = threadIdx.x & 63;
    const int W = TPBB / 64;                      // 8 waves

    for (int kb = k0 + wid; kb < k1; kb += 4 * W) {
        int ka = kb, kB = kb + W, kc = kb + 2 * W, kd = kb + 3 * W;
        bool e1 = kB < k1, e2 = kc < k1, e3 = kd < k1;

        unsigned n0 = cnt_table[(size_t)ka * nb + b];
        unsigned n1 = e1 ? cnt_table[(size_t)kB * nb + b] : 0u;
        unsigned n2 = e2 ? cnt_table[(size_t)kc * nb + b] : 0u;
        unsigned n3 = e3 ? cnt_table[(size_t)kd * nb + b] : 0u;

        const uint2* r0 = records + ((size_t)ka * nb + b) * cap;
        const uint2* r1 = e1 ? records + ((size_t)kB * nb + b) * cap : r0;
        const uint2* r2 = e2 ? records + ((size_t)kc * nb + b) * cap : r0;
        const uint2* r3 = e3 ? records + ((size_t)kd * nb + b) * cap : r0;
        const uint4* q0 = (const uint4*)r0;
        const uint4* q1 = (const uint4*)r1;
        const uint4* q2 = (const uint4*)r2;
        const uint4* q3 = (const uint4*)r3;

        unsigned h0 = n0 >> 1, h1 = n1 >> 1, h2 = n2 >> 1, h3 = n3 >> 1;
        unsigned hm = max(max(h0, h1), max(h2, h3));

        for (unsigned i = lane; i < hm; i += 64) {
            uint4 v0 = q0[h0 ? min(i, h0 - 1u) : 0u];
            uint4 v1 = q1[h1 ? min(i, h1 - 1u) : 0u];
            uint4 v2 = q2[h2 ? min(i, h2 - 1u) : 0u];
            uint4 v3 = q3[h3 ? min(i, h3 - 1u) : 0u];
            if (i < h0) { acc_rec(acc, v0.x, v0.y); acc_rec(acc, v0.z, v0.w); }
            if (i < h1) { acc_rec(acc, v1.x, v1.y); acc_rec(acc, v1.z, v1.w); }
            if (i < h2) { acc_rec(acc, v2.x, v2.y); acc_rec(acc, v2.z, v2.w); }
            if (i < h3) { acc_rec(acc, v3.x, v3.y); acc_rec(acc, v3.z, v3.w); }
        }
        if (lane == 0) {
            if (n0 & 1u) { uint2 t = r0[n0 - 1]; acc_rec(acc, t.x, t.y); }
            if (n1 & 1u) { uint2 t = r1[n1 - 1]; acc_rec(acc, t.x, t.y); }
            if (n2 & 1u) { uint2 t = r2[n2 - 1]; acc_rec(acc, t.x, t.y); }
            if (n3 & 1u) { uint2 t = r3[n3 - 1]; acc_rec(acc, t.x, t.y); }
        }
    }
    __syncthreads();

    int* dst = partial + (size_t)blockIdx.x * 3 * CHUNK;
    for (int i = threadIdx.x; i < 3 * CHUNK; i += TPBB) dst[i] = acc[i];
}

// fin_force: blocks [0,nfblk) reduce force partials (exact integer sums);
// blocks [nfblk, nfblk+64) do the energy reduction (one wave per graph).
__global__ __launch_bounds__(256) void fin_force(
    const int* __restrict__ partial, const float* __restrict__ ovf,
    const float* __restrict__ e_part,
    float* __restrict__ force, float* __restrict__ energy,
    int n_atoms, int nslice, int nblkA, int nfblk)
{
    if ((int)blockIdx.x >= nfblk) {
        int g = (blockIdx.x - nfblk) * 4 + (threadIdx.x >> 6);   // graph per wave
        int lane = threadIdx.x & 63;
        float s = 0.f;
        for (int k = lane; k < nblkA; k += 64)
            s += e_part[(size_t)k * N_GRAPHS_C + g];
        for (int off = 32; off > 0; off >>= 1) s += __shfl_down(s, off, 64);
        if (lane == 0) energy[g] = s;
        return;
    }
    int a = blockIdx.x * 256 + threadIdx.x;
    if (a >= n_atoms) return;
    int b = a >> CHUNK_LOG, l = a & (CHUNK - 1);
    long long sx = 0, sy = 0, sz = 0;
    const int* p = partial + (size_t)b * nslice * 3 * CHUNK + l;
    for (int s = 0; s < nslice; ++s) {
        const int* ps = p + (size_t)s * 3 * CHUNK;
        sx += ps[0]; sy += ps[CHUNK]; sz += ps[2 * CHUNK];
    }
    force[3 * a + 0] = ovf[3 * a + 0] + (float)sx * FP_INV;
    force[3 * a + 1] = ovf[3 * a + 1] + (float)sy * FP_INV;
    force[3 * a + 2] = ovf[3 * a + 2] + (float)sz * FP_INV;
}

// ================= fallback: chunk-scan path =================
__global__ __launch_bounds__(1024) void chunk_kernel(
    const float* __restrict__ dij, const float* __restrict__ q,
    const float* __restrict__ g_ewald,
    const int* __restrict__ row, const int* __restrict__ col,
    float* __restrict__ partial, int n_edges, int n_chunks, int n_slices)
{
    __shared__ float acc[CHUNK * 4];
    int c = blockIdx.x % n_chunks;
    int p = blockIdx.x / n_chunks;
    int cbase = c << CHUNK_LOG;
    for (int i = threadIdx.x; i < CHUNK * 4; i += 1024) acc[i] = 0.f;
    __syncthreads();
    const float gA = g_ewald[0] * 1e-10f;
    int n4 = (n_edges + 3) >> 2;
    int g0 = (int)((long long)p * n4 / n_slices);
    int g1 = (int)((long long)(p + 1) * n4 / n_slices);
    const int4* row4 = (const int4*)row;
    const int4* col4 = (const int4*)col;
    for (int g = g0 + threadIdx.x; g < g1; g += 1024) {
        int4 r4 = row4[g];
        int4 c4 = col4[g];
        int rr[4] = {r4.x, r4.y, r4.z, r4.w};
        int cc[4] = {c4.x, c4.y, c4.z, c4.w};
        #pragma unroll
        for (int j = 0; j < 4; ++j) {
            int e = 4 * g + j;
            if (e >= n_edges) break;
            int rl = rr[j] - cbase;
            int cl = cc[j] - cbase;
            bool hr = (unsigned)rl < (unsigned)CHUNK;
            bool hc = (unsigned)cl < (unsigned)CHUNK;
            if (!(hr || hc)) continue;
            float fx, fy, fz, ec;
            edge_math(dij[3 * e], dij[3 * e + 1], dij[3 * e + 2],
                      q[rr[j]], q[cc[j]], gA, fx, fy, fz, ec);
            if (hr) {
                atomicAdd(&acc[4 * rl + 0], fx);
                atomicAdd(&acc[4 * rl + 1], fy);
                atomicAdd(&acc[4 * rl + 2], fz);
                atomicAdd(&acc[4 * rl + 3], ec);
            }
            if (hc) {
                atomicAdd(&acc[4 * cl + 0], -fx);
                atomicAdd(&acc[4 * cl + 1], -fy);
                atomicAdd(&acc[4 * cl + 2], -fz);
            }
        }
    }
    __syncthreads();
    float4* dst = (float4*)partial + (size_t)(c * n_slices + p) * CHUNK;
    const float4* src = (const float4*)acc;
    for (int i = threadIdx.x; i < CHUNK; i += 1024) dst[i] = src[i];
}

__global__ __launch_bounds__(256) void finalize_kernel(
    const float* __restrict__ partial, const int* __restrict__ batch,
    float* __restrict__ energy, float* __restrict__ force,
    int n_atoms, int n_slices)
{
    int i = blockIdx.x * blockDim.x + threadIdx.x;
    float fx = 0.f, fy = 0.f, fz = 0.f, en = 0.f;
    if (i < n_atoms) {
        int c = i >> CHUNK_LOG;
        int l = i & (CHUNK - 1);
        const float4* base = (const float4*)partial + (size_t)c * n_slices * CHUNK + l;
        for (int p = 0; p < n_slices; ++p) {
            float4 v = base[(size_t)p * CHUNK];
            fx += v.x; fy += v.y; fz += v.z; en += v.w;
        }
        force[3 * i + 0] = fx;
        force[3 * i + 1] = fy;
        force[3 * i + 2] = fz;
    }
    int ic = i < n_atoms ? i : (n_atoms - 1);
    int b = batch[ic];
    float v = (i < n_atoms) ? en : 0.0f;
    int b0 = __shfl(b, 0, 64);
    unsigned long long m = __ballot(b == b0);
    if (m == ~0ull) {
        for (int off = 32; off > 0; off >>= 1)
            v += __shfl_down(v, off, 64);
        if ((threadIdx.x & 63) == 0) atomicAdd(&energy[b0], v);
    } else {
        atomicAdd(&energy[b], v);
    }
}

extern "C" void kernel_launch(void* const* d_in, const int* in_sizes, int n_in,
                              void* d_out, int out_size, void* d_ws, size_t ws_size,
                              hipStream_t stream) {
    const float* dij     = (const float*)d_in[0];
    const float* q       = (const float*)d_in[1];
    const float* g_ewald = (const float*)d_in[2];
    const int*   row     = (const int*)d_in[3];
    const int*   col     = (const int*)d_in[4];
    const int*   batch   = (const int*)d_in[5];

    int n_edges = in_sizes[0] / 3;
    int n_atoms = in_sizes[1];

    float* energy = (float*)d_out;               // [256]
    float* force  = (float*)d_out + N_GRAPHS_C;  // [n_atoms*3]

    int nb = (n_atoms + CHUNK - 1) >> CHUNK_LOG;            // 49
    int n4 = n_edges >> 2;

    size_t sz_partial = (size_t)nb * NSLICE * 3 * CHUNK * sizeof(int);  // ~38.5 MB
    size_t sz_ovf     = (size_t)3 * n_atoms * sizeof(float);
    size_t sz_qg      = (size_t)n_atoms * sizeof(float2);

    // Adaptive tile selection. nb=49 buckets: tile 1024 -> mean 167/run,
    // sigma ~13 -> cap 256 is +7 sigma; tile 2048 -> mean 334, cap 512 = +10.
    // Rare overflow goes through ovf atomics (still correct).
    const int  tile_sel[2]   = {1024, 2048};
    const int  mincap_sel[2] = {224, 416};
    const int  capmax_sel[2] = {256, 512};

    int tile_g = 0, cap = 0, nblkA = 0;
    size_t sz_epart = 0, sz_cnt = 0;
    for (int t = 0; t < 2 && tile_g == 0; ++t) {
        int nba = (n4 + tile_sel[t] - 1) / tile_sel[t];
        size_t se = (size_t)nba * N_GRAPHS_C * sizeof(float);
        size_t sc = (size_t)nba * nb * sizeof(unsigned);
        size_t fixed = ((sz_partial + 255) & ~(size_t)255) +
                       ((se         + 255) & ~(size_t)255) +
                       ((sc         + 255) & ~(size_t)255) +
                       ((sz_ovf     + 255) & ~(size_t)255) +
                       ((sz_qg      + 255) & ~(size_t)255) + 512;
        if ((long long)ws_size > (long long)fixed) {
            long long c = ((long long)ws_size - (long long)fixed) /
                          ((long long)nba * nb * 8);
            c = (c / 32) * 32;
            if (c > capmax_sel[t]) c = capmax_sel[t];
            if (c >= mincap_sel[t]) {
                tile_g = tile_sel[t]; cap = (int)c; nblkA = nba;
                sz_epart = se; sz_cnt = sc;
            }
        }
    }

    bool fast = (nb <= MAXB) && ((n_edges & 3) == 0) && (tile_g > 0) &&
                ((tile_g % TPA) == 0);

    if (fast) {
        char* ws = (char*)d_ws;
        size_t off = 0;
        uint2*    records  = (uint2*)(ws + off);
        off += (size_t)nblkA * nb * cap * 8;   off = (off + 255) & ~(size_t)255;
        int*      partial  = (int*)(ws + off);
        off += sz_partial;                     off = (off + 255) & ~(size_t)255;
        float*    e_part   = (float*)(ws + off);
        off += sz_epart;                       off = (off + 255) & ~(size_t)255;
        unsigned* cnt_tab  = (unsigned*)(ws + off);
        off += sz_cnt;                         off = (off + 255) & ~(size_t)255;
        float*    ovf      = (float*)(ws + off);
        off += sz_ovf;                         off = (off + 255) & ~(size_t)255;
        float2*   qg       = (float2*)(ws + off);

        prep_qg<<<(n_atoms + 255) / 256, 256, 0, stream>>>(q, batch, qg, ovf, n_atoms);

        passA<<<nblkA, TPA, 0, stream>>>(
            dij, qg, g_ewald, row, col,
            records, cap, cnt_tab, e_part, ovf, n_edges, nb, tile_g);

        passB<<<nb * NSLICE, TPBB, 0, stream>>>(
            records, cap, cnt_tab, partial, nblkA, nb, NSLICE);

        int nfblk = (n_atoms + 255) / 256;
        fin_force<<<nfblk + N_GRAPHS_C / 4, 256, 0, stream>>>(
            partial, ovf, e_part, force, energy, n_atoms, NSLICE, nblkA, nfblk);
    } else {
        size_t need_chunk = (size_t)nb * NSLICE_FB * CHUNK * 4 * sizeof(float);
        if (ws_size >= need_chunk) {
            hipMemsetAsync(d_out, 0, N_GRAPHS_C * sizeof(float), stream);
            chunk_kernel<<<nb * NSLICE_FB, 1024, 0, stream>>>(
                dij, q, g_ewald, row, col, (float*)d_ws, n_edges, nb, NSLICE_FB);
            finalize_kernel<<<(n_atoms + 255) / 256, 256, 0, stream>>>(
                (const float*)d_ws, batch, energy, force, n_atoms, NSLICE_FB);
        }
    }
}

// Round 8
// 343.334 us; speedup vs baseline: 1.4394x; 1.0260x over previous
//
#include <hip/hip_runtime.h>
#include <hip/hip_fp16.h>

#define N_GRAPHS_C 256
#define CHUNK_LOG 12
#define CHUNK (1 << CHUNK_LOG)   // 4096 atoms per bucket
#define MAXB 64
#define NSLICE 12                // passB slices per bucket (49 KB LDS -> 3 blocks/CU)
#define NSLICE_FB 10
#define TPA 256
#define TPBB 512
#define SD 64                    // LDS staging depth per bucket (mean 42/phase, +3.5 sigma)
#define PSTR (CHUNK + 8)         // passB plane stride: banks idx, idx+8, idx+16
#define FP_SCALE 1024.0f
#define FP_INV   (1.0f / 1024.0f)

// ---------------- shared per-edge math ----------------
// Units: Angstrom, electron charge, eV (avoids fp32 denormals from the
// reference's SI-unit charges; algebraically identical).
__device__ __forceinline__ void edge_math(
    float dx, float dy, float dz, float qr, float qc, float gA,
    float& fx, float& fy, float& fz, float& ecoul)
{
    const float KEV = (float)(8987551792.3 * 1.602176634e-9); // 14.3996 eV*A/e^2
    float r2 = dx * dx + dy * dy + dz * dz;
    float inv_r = rsqrtf(r2);
    float rA = r2 * inv_r;

    float pref = KEV * qr * qc * inv_r;

    float damp = 1.0f;
    if (rA < 2.2f)
        damp = __expf(-18.7f * (2.2f - rA) * (1.0f / 2.2f));

    float grij = gA * rA;
    float expm2 = __expf(-grij * grij);
    float t = 1.0f / (1.0f + 0.3275911f * grij);
    float erfc = t * (0.254829592f +
                 t * (-0.284496736f +
                 t * (1.421413741f +
                 t * (-1.453152027f +
                 t * 1.061405429f)))) * expm2;

    ecoul = pref * (0.5f * damp + (erfc - 1.0f));
    float S = damp + erfc + 2.0f * grij * expm2 - 1.0f;
    float fs = pref * S * (inv_r * inv_r);
    fx = dx * fs; fy = dy * fs; fz = dz * fs;
}

__device__ __forceinline__ uint2 pack_rec(float fx, float fy, float fz, unsigned lid)
{
    uint2 u;
    u.x = __builtin_bit_cast(unsigned, __floats2half2_rn(fx, fy));
    u.y = (__builtin_bit_cast(unsigned, __floats2half2_rn(fz, 0.0f)) & 0xFFFFu) |
          (lid << 16);
    return u;
}

// passB record accumulate: f16 record -> i32 fixed-point (scale 2^10) into
// three PADDED planes (stride CHUNK+8) via native integer LDS atomics.
// Unpadded (stride 4096 = 0 mod 32 banks) all 3 atomics of a record hit the
// SAME bank -> serialized 3-chain per record, immune to MLP/occupancy (the
// r3/r7 null signature). Padded: banks idx, idx+8, idx+16.
__device__ __forceinline__ void acc_rec(int* acc, unsigned w0, unsigned w1)
{
    float2 xy = __half22float2(__builtin_bit_cast(__half2, w0));
    float fz = __half2float(__builtin_bit_cast(__half2, w1).x);   // low half
    unsigned idx = w1 >> 16;
    atomicAdd(&acc[idx],            __float2int_rn(xy.x * FP_SCALE));
    atomicAdd(&acc[PSTR + idx],     __float2int_rn(xy.y * FP_SCALE));
    atomicAdd(&acc[2 * PSTR + idx], __float2int_rn(fz   * FP_SCALE));
}

// prep: fuse q[] and batch[] into one 8 B table so passA does 2 scattered
// gathers per edge instead of 3. Also zeroes ovf[] (replaces a memset launch).
__global__ __launch_bounds__(256) void prep_qg(
    const float* __restrict__ q, const int* __restrict__ batch,
    float2* __restrict__ qg, float* __restrict__ ovf, int n_atoms)
{
    int i = blockIdx.x * 256 + threadIdx.x;
    if (i < n_atoms) {
        qg[i] = make_float2(q[i], __int_as_float(batch[i]));
        ovf[3 * i + 0] = 0.f;
        ovf[3 * i + 1] = 0.f;
        ovf[3 * i + 2] = 0.f;
    }
}

// ================= fast path =================
// passA with LDS-staged coalesced record flush (r6: -38us vs scattered
// stores). Stage rows padded to SD+1 for partial bank de-aliasing.
__global__ __launch_bounds__(TPA) void passA(
    const float* __restrict__ dij, const float2* __restrict__ qg,
    const float* __restrict__ g_ewald,
    const int* __restrict__ row, const int* __restrict__ col,
    uint2* __restrict__ records, int cap,
    unsigned* __restrict__ cnt_table,
    float* __restrict__ e_part,
    float* __restrict__ ovf,
    int n_edges, int nb, int tile_g)
{
    __shared__ uint2    stage[MAXB][SD + 1];    // +1 pad: bank de-aliasing
    __shared__ unsigned scnt[MAXB];             // per-phase stage counts
    __shared__ unsigned cnt[MAXB];              // per-block reserved slots
    __shared__ float    e_graph[4 * N_GRAPHS_C];

    int tid  = threadIdx.x;
    int wid  = tid >> 6;
    int lane = tid & 63;
    if (tid < MAXB) { scnt[tid] = 0u; cnt[tid] = 0u; }
    for (int i = tid; i < 4 * N_GRAPHS_C; i += TPA) e_graph[i] = 0.f;
    __syncthreads();

    float* e_my = &e_graph[wid * N_GRAPHS_C];

    int n4 = n_edges >> 2;
    int gbase = blockIdx.x * tile_g;
    int g1 = min(gbase + tile_g, n4);
    int nph = tile_g / TPA;

    const int4* row4 = (const int4*)row;
    const int4* col4 = (const int4*)col;
    const float4* dij4 = (const float4*)dij;

    const float gA = g_ewald[0] * 1e-10f;    // 1/m -> 1/Angstrom
    size_t blk_base = (size_t)blockIdx.x * nb * cap;

    // prologue: indices + gathers for phase 0
    int4 r_cur = make_int4(0, 0, 0, 0), c_cur = make_int4(0, 0, 0, 0);
    float2 vr_cur[4], vc_cur[4];
    {
        int g = gbase + tid;
        if (g < g1) { r_cur = row4[g]; c_cur = col4[g]; }
        vr_cur[0] = qg[r_cur.x]; vc_cur[0] = qg[c_cur.x];
        vr_cur[1] = qg[r_cur.y]; vc_cur[1] = qg[c_cur.y];
        vr_cur[2] = qg[r_cur.z]; vc_cur[2] = qg[c_cur.z];
        vr_cur[3] = qg[r_cur.w]; vc_cur[3] = qg[c_cur.w];
    }

    for (int p = 0; p < nph; ++p) {
        int g = gbase + p * TPA + tid;

        // next phase's indices (issued early; qg[0] dummies past the end)
        int4 r_nxt = make_int4(0, 0, 0, 0), c_nxt = make_int4(0, 0, 0, 0);
        if (p + 1 < nph && g + TPA < g1) {
            r_nxt = row4[g + TPA]; c_nxt = col4[g + TPA];
        }

        if (g < g1) {
            float4 d0 = dij4[3 * g + 0];
            float4 d1 = dij4[3 * g + 1];
            float4 d2 = dij4[3 * g + 2];
            float ex[4] = {d0.x, d0.w, d1.z, d2.y};
            float ey[4] = {d0.y, d1.x, d1.w, d2.z};
            float ez[4] = {d0.z, d1.y, d2.x, d2.w};
            int rr[4] = {r_cur.x, r_cur.y, r_cur.z, r_cur.w};
            int cc[4] = {c_cur.x, c_cur.y, c_cur.z, c_cur.w};

            #pragma unroll
            for (int j = 0; j < 4; ++j) {
                int r = rr[j], c = cc[j];
                float fx, fy, fz, ec;
                edge_math(ex[j], ey[j], ez[j], vr_cur[j].x, vc_cur[j].x, gA,
                          fx, fy, fz, ec);

                atomicAdd(&e_my[__float_as_int(vr_cur[j].y)], ec);

                int br = r >> CHUNK_LOG, bc = c >> CHUNK_LOG;
                unsigned pr = atomicAdd(&scnt[br], 1u);
                unsigned pc = atomicAdd(&scnt[bc], 1u);
                if (pr < SD)
                    stage[br][pr] = pack_rec(fx, fy, fz, (unsigned)(r & (CHUNK - 1)));
                else {
                    atomicAdd(&ovf[3 * r + 0], fx);
                    atomicAdd(&ovf[3 * r + 1], fy);
                    atomicAdd(&ovf[3 * r + 2], fz);
                }
                if (pc < SD)
                    stage[bc][pc] = pack_rec(-fx, -fy, -fz, (unsigned)(c & (CHUNK - 1)));
                else {
                    atomicAdd(&ovf[3 * c + 0], -fx);
                    atomicAdd(&ovf[3 * c + 1], -fy);
                    atomicAdd(&ovf[3 * c + 2], -fz);
                }
            }
        }

        // issue next phase's gathers now: latency hides under the flush
        float2 vr_n[4], vc_n[4];
        vr_n[0] = qg[r_nxt.x]; vc_n[0] = qg[c_nxt.x];
        vr_n[1] = qg[r_nxt.y]; vc_n[1] = qg[c_nxt.y];
        vr_n[2] = qg[r_nxt.z]; vc_n[2] = qg[c_nxt.z];
        vr_n[3] = qg[r_nxt.w]; vc_n[3] = qg[c_nxt.w];

        __syncthreads();

        // wave-cooperative flush: wave handles buckets wid, wid+4, ...
        for (int b = wid; b < nb; b += TPA / 64) {
            unsigned m = min(scnt[b], (unsigned)SD);
            unsigned base = 0;
            if (lane == 0) base = atomicAdd(&cnt[b], m);
            base = (unsigned)__shfl((int)base, 0, 64);
            for (unsigned i = lane; i < m; i += 64) {
                uint2 rv = stage[b][i];
                unsigned slot = base + i;
                if (slot < (unsigned)cap) {
                    records[blk_base + (size_t)b * cap + slot] = rv;
                } else {
                    float2 xy = __half22float2(__builtin_bit_cast(__half2, rv.x));
                    float fzv = __half2float(__builtin_bit_cast(__half2, rv.y).x);
                    int atom = (b << CHUNK_LOG) + (int)(rv.y >> 16);
                    atomicAdd(&ovf[3 * atom + 0], xy.x);
                    atomicAdd(&ovf[3 * atom + 1], xy.y);
                    atomicAdd(&ovf[3 * atom + 2], fzv);
                }
            }
            if (lane == 0) scnt[b] = 0u;
        }
        __syncthreads();

        r_cur = r_nxt; c_cur = c_nxt;
        #pragma unroll
        for (int j = 0; j < 4; ++j) { vr_cur[j] = vr_n[j]; vc_cur[j] = vc_n[j]; }
    }

    if (tid < nb) cnt_table[(size_t)blockIdx.x * nb + tid] = min(cnt[tid], (unsigned)cap);
    for (int g2 = tid; g2 < N_GRAPHS_C; g2 += TPA)
        e_part[(size_t)blockIdx.x * N_GRAPHS_C + g2] =
            e_graph[g2] + e_graph[N_GRAPHS_C + g2] +
            e_graph[2 * N_GRAPHS_C + g2] + e_graph[3 * N_GRAPHS_C + g2];
}

// passB: block (b,s). 4 runs concurrently per wave (independent loads in
// flight), exec-masked native-i32 accumulates into bank-padded planes.
// Writeout compacts the padded planes back to the dense [3*CHUNK] layout.
__global__ __launch_bounds__(TPBB) void passB(
    const uint2* __restrict__ records, int cap,
    const unsigned* __restrict__ cnt_table,
    int* __restrict__ partial, int nblkA, int nb, int nslice)
{
    __shared__ int acc[3 * PSTR];

    int b = blockIdx.x / nslice;
    int s = blockIdx.x % nslice;
    int k0 = (int)((long long)s * nblkA / nslice);
    int k1 = (int)((long long)(s + 1) * nblkA / nslice);

    for (int i = threadIdx.x; i < 3 * PSTR; i += TPBB) acc[i] = 0;
    __syncthreads();

    int wid  = threadIdx.x >> 6;
    int lane = threadIdx.x & 63;
    const int W = TPBB / 64;                      // 8 waves

    for (int kb = k0 + wid; kb < k1; kb += 4 * W) {
        int ka = kb, kB = kb + W, kc = kb + 2 * W, kd = kb + 3 * W;
        bool e1 = kB < k1, e2 = kc < k1, e3 = kd < k1;

        unsigned n0 = cnt_table[(size_t)ka * nb + b];
        unsigned n1 = e1 ? cnt_table[(size_t)kB * nb + b] : 0u;
        unsigned n2 = e2 ? cnt_table[(size_t)kc * nb + b] : 0u;
        unsigned n3 = e3 ? cnt_table[(size_t)kd * nb + b] : 0u;

        const uint2* r0 = records + ((size_t)ka * nb + b) * cap;
        const uint2* r1 = e1 ? records + ((size_t)kB * nb + b) * cap : r0;
        const uint2* r2 = e2 ? records + ((size_t)kc * nb + b) * cap : r0;
        const uint2* r3 = e3 ? records + ((size_t)kd * nb + b) * cap : r0;
        const uint4* q0 = (const uint4*)r0;
        const uint4* q1 = (const uint4*)r1;
        const uint4* q2 = (const uint4*)r2;
        const uint4* q3 = (const uint4*)r3;

        unsigned h0 = n0 >> 1, h1 = n1 >> 1, h2 = n2 >> 1, h3 = n3 >> 1;
        unsigned hm = max(max(h0, h1), max(h2, h3));

        for (unsigned i = lane; i < hm; i += 64) {
            uint4 v0 = q0[h0 ? min(i, h0 - 1u) : 0u];
            uint4 v1 = q1[h1 ? min(i, h1 - 1u) : 0u];
            uint4 v2 = q2[h2 ? min(i, h2 - 1u) : 0u];
            uint4 v3 = q3[h3 ? min(i, h3 - 1u) : 0u];
            if (i < h0) { acc_rec(acc, v0.x, v0.y); acc_rec(acc, v0.z, v0.w); }
            if (i < h1) { acc_rec(acc, v1.x, v1.y); acc_rec(acc, v1.z, v1.w); }
            if (i < h2) { acc_rec(acc, v2.x, v2.y); acc_rec(acc, v2.z, v2.w); }
            if (i < h3) { acc_rec(acc, v3.x, v3.y); acc_rec(acc, v3.z, v3.w); }
        }
        if (lane == 0) {
            if (n0 & 1u) { uint2 t = r0[n0 - 1]; acc_rec(acc, t.x, t.y); }
            if (n1 & 1u) { uint2 t = r1[n1 - 1]; acc_rec(acc, t.x, t.y); }
            if (n2 & 1u) { uint2 t = r2[n2 - 1]; acc_rec(acc, t.x, t.y); }
            if (n3 & 1u) { uint2 t = r3[n3 - 1]; acc_rec(acc, t.x, t.y); }
        }
    }
    __syncthreads();

    // compact padded planes -> dense [3*CHUNK] partial
    int* dst = partial + (size_t)blockIdx.x * 3 * CHUNK;
    for (int i = threadIdx.x; i < 3 * CHUNK; i += TPBB) {
        int pl = i >> CHUNK_LOG;
        int ofs = i & (CHUNK - 1);
        dst[i] = acc[pl * PSTR + ofs];
    }
}

// fin_force: blocks [0,nfblk) reduce force partials (exact integer sums);
// blocks [nfblk, nfblk+64) do the energy reduction (one wave per graph).
__global__ __launch_bounds__(256) void fin_force(
    const int* __restrict__ partial, const float* __restrict__ ovf,
    const float* __restrict__ e_part,
    float* __restrict__ force, float* __restrict__ energy,
    int n_atoms, int nslice, int nblkA, int nfblk)
{
    if ((int)blockIdx.x >= nfblk) {
        int g = (blockIdx.x - nfblk) * 4 + (threadIdx.x >> 6);   // graph per wave
        int lane = threadIdx.x & 63;
        float s = 0.f;
        for (int k = lane; k < nblkA; k += 64)
            s += e_part[(size_t)k * N_GRAPHS_C + g];
        for (int off = 32; off > 0; off >>= 1) s += __shfl_down(s, off, 64);
        if (lane == 0) energy[g] = s;
        return;
    }
    int a = blockIdx.x * 256 + threadIdx.x;
    if (a >= n_atoms) return;
    int b = a >> CHUNK_LOG, l = a & (CHUNK - 1);
    long long sx = 0, sy = 0, sz = 0;
    const int* p = partial + (size_t)b * nslice * 3 * CHUNK + l;
    for (int s = 0; s < nslice; ++s) {
        const int* ps = p + (size_t)s * 3 * CHUNK;
        sx += ps[0]; sy += ps[CHUNK]; sz += ps[2 * CHUNK];
    }
    force[3 * a + 0] = ovf[3 * a + 0] + (float)sx * FP_INV;
    force[3 * a + 1] = ovf[3 * a + 1] + (float)sy * FP_INV;
    force[3 * a + 2] = ovf[3 * a + 2] + (float)sz * FP_INV;
}

// ================= fallback: chunk-scan path =================
__global__ __launch_bounds__(1024) void chunk_kernel(
    const float* __restrict__ dij, const float* __restrict__ q,
    const float* __restrict__ g_ewald,
    const int* __restrict__ row, const int* __restrict__ col,
    float* __restrict__ partial, int n_edges, int n_chunks, int n_slices)
{
    __shared__ float acc[CHUNK * 4];
    int c = blockIdx.x % n_chunks;
    int p = blockIdx.x / n_chunks;
    int cbase = c << CHUNK_LOG;
    for (int i = threadIdx.x; i < CHUNK * 4; i += 1024) acc[i] = 0.f;
    __syncthreads();
    const float gA = g_ewald[0] * 1e-10f;
    int n4 = (n_edges + 3) >> 2;
    int g0 = (int)((long long)p * n4 / n_slices);
    int g1 = (int)((long long)(p + 1) * n4 / n_slices);
    const int4* row4 = (const int4*)row;
    const int4* col4 = (const int4*)col;
    for (int g = g0 + threadIdx.x; g < g1; g += 1024) {
        int4 r4 = row4[g];
        int4 c4 = col4[g];
        int rr[4] = {r4.x, r4.y, r4.z, r4.w};
        int cc[4] = {c4.x, c4.y, c4.z, c4.w};
        #pragma unroll
        for (int j = 0; j < 4; ++j) {
            int e = 4 * g + j;
            if (e >= n_edges) break;
            int rl = rr[j] - cbase;
            int cl = cc[j] - cbase;
            bool hr = (unsigned)rl < (unsigned)CHUNK;
            bool hc = (unsigned)cl < (unsigned)CHUNK;
            if (!(hr || hc)) continue;
            float fx, fy, fz, ec;
            edge_math(dij[3 * e], dij[3 * e + 1], dij[3 * e + 2],
                      q[rr[j]], q[cc[j]], gA, fx, fy, fz, ec);
            if (hr) {
                atomicAdd(&acc[4 * rl + 0], fx);
                atomicAdd(&acc[4 * rl + 1], fy);
                atomicAdd(&acc[4 * rl + 2], fz);
                atomicAdd(&acc[4 * rl + 3], ec);
            }
            if (hc) {
                atomicAdd(&acc[4 * cl + 0], -fx);
                atomicAdd(&acc[4 * cl + 1], -fy);
                atomicAdd(&acc[4 * cl + 2], -fz);
            }
        }
    }
    __syncthreads();
    float4* dst = (float4*)partial + (size_t)(c * n_slices + p) * CHUNK;
    const float4* src = (const float4*)acc;
    for (int i = threadIdx.x; i < CHUNK; i += 1024) dst[i] = src[i];
}

__global__ __launch_bounds__(256) void finalize_kernel(
    const float* __restrict__ partial, const int* __restrict__ batch,
    float* __restrict__ energy, float* __restrict__ force,
    int n_atoms, int n_slices)
{
    int i = blockIdx.x * blockDim.x + threadIdx.x;
    float fx = 0.f, fy = 0.f, fz = 0.f, en = 0.f;
    if (i < n_atoms) {
        int c = i >> CHUNK_LOG;
        int l = i & (CHUNK - 1);
        const float4* base = (const float4*)partial + (size_t)c * n_slices * CHUNK + l;
        for (int p = 0; p < n_slices; ++p) {
            float4 v = base[(size_t)p * CHUNK];
            fx += v.x; fy += v.y; fz += v.z; en += v.w;
        }
        force[3 * i + 0] = fx;
        force[3 * i + 1] = fy;
        force[3 * i + 2] = fz;
    }
    int ic = i < n_atoms ? i : (n_atoms - 1);
    int b = batch[ic];
    float v = (i < n_atoms) ? en : 0.0f;
    int b0 = __shfl(b, 0, 64);
    unsigned long long m = __ballot(b == b0);
    if (m == ~0ull) {
        for (int off = 32; off > 0; off >>= 1)
            v += __shfl_down(v, off, 64);
        if ((threadIdx.x & 63) == 0) atomicAdd(&energy[b0], v);
    } else {
        atomicAdd(&energy[b], v);
    }
}

extern "C" void kernel_launch(void* const* d_in, const int* in_sizes, int n_in,
                              void* d_out, int out_size, void* d_ws, size_t ws_size,
                              hipStream_t stream) {
    const float* dij     = (const float*)d_in[0];
    const float* q       = (const float*)d_in[1];
    const float* g_ewald = (const float*)d_in[2];
    const int*   row     = (const int*)d_in[3];
    const int*   col     = (const int*)d_in[4];
    const int*   batch   = (const int*)d_in[5];

    int n_edges = in_sizes[0] / 3;
    int n_atoms = in_sizes[1];

    float* energy = (float*)d_out;               // [256]
    float* force  = (float*)d_out + N_GRAPHS_C;  // [n_atoms*3]

    int nb = (n_atoms + CHUNK - 1) >> CHUNK_LOG;            // 49
    int n4 = n_edges >> 2;

    size_t sz_partial = (size_t)nb * NSLICE * 3 * CHUNK * sizeof(int);  // ~29 MB
    size_t sz_ovf     = (size_t)3 * n_atoms * sizeof(float);
    size_t sz_qg      = (size_t)n_atoms * sizeof(float2);

    // Adaptive tile selection. nb=49 buckets: tile 1024 -> mean 167/run,
    // sigma ~13 -> cap 256 is +7 sigma; tile 2048 -> mean 334, cap 512 = +10.
    // Rare overflow goes through ovf atomics (still correct).
    const int  tile_sel[2]   = {1024, 2048};
    const int  mincap_sel[2] = {224, 416};
    const int  capmax_sel[2] = {256, 512};

    int tile_g = 0, cap = 0, nblkA = 0;
    size_t sz_epart = 0, sz_cnt = 0;
    for (int t = 0; t < 2 && tile_g == 0; ++t) {
        int nba = (n4 + tile_sel[t] - 1) / tile_sel[t];
        size_t se = (size_t)nba * N_GRAPHS_C * sizeof(float);
        size_t sc = (size_t)nba * nb * sizeof(unsigned);
        size_t fixed = ((sz_partial + 255) & ~(size_t)255) +
                       ((se         + 255) & ~(size_t)255) +
                       ((sc         + 255) & ~(size_t)255) +
                       ((sz_ovf     + 255) & ~(size_t)255) +
                       ((sz_qg      + 255) & ~(size_t)255) + 512;
        if ((long long)ws_size > (long long)fixed) {
            long long c = ((long long)ws_size - (long long)fixed) /
                          ((long long)nba * nb * 8);
            c = (c / 32) * 32;
            if (c > capmax_sel[t]) c = capmax_sel[t];
            if (c >= mincap_sel[t]) {
                tile_g = tile_sel[t]; cap = (int)c; nblkA = nba;
                sz_epart = se; sz_cnt = sc;
            }
        }
    }

    bool fast = (nb <= MAXB) && ((n_edges & 3) == 0) && (tile_g > 0) &&
                ((tile_g % TPA) == 0);

    if (fast) {
        char* ws = (char*)d_ws;
        size_t off = 0;
        uint2*    records  = (uint2*)(ws + off);
        off += (size_t)nblkA * nb * cap * 8;   off = (off + 255) & ~(size_t)255;
        int*      partial  = (int*)(ws + off);
        off += sz_partial;                     off = (off + 255) & ~(size_t)255;
        float*    e_part   = (float*)(ws + off);
        off += sz_epart;                       off = (off + 255) & ~(size_t)255;
        unsigned* cnt_tab  = (unsigned*)(ws + off);
        off += sz_cnt;                         off = (off + 255) & ~(size_t)255;
        float*    ovf      = (float*)(ws + off);
        off += sz_ovf;                         off = (off + 255) & ~(size_t)255;
        float2*   qg       = (float2*)(ws + off);

        prep_qg<<<(n_atoms + 255) / 256, 256, 0, stream>>>(q, batch, qg, ovf, n_atoms);

        passA<<<nblkA, TPA, 0, stream>>>(
            dij, qg, g_ewald, row, col,
            records, cap, cnt_tab, e_part, ovf, n_edges, nb, tile_g);

        passB<<<nb * NSLICE, TPBB, 0, stream>>>(
            records, cap, cnt_tab, partial, nblkA, nb, NSLICE);

        int nfblk = (n_atoms + 255) / 256;
        fin_force<<<nfblk + N_GRAPHS_C / 4, 256, 0, stream>>>(
            partial, ovf, e_part, force, energy, n_atoms, NSLICE, nblkA, nfblk);
    } else {
        size_t need_chunk = (size_t)nb * NSLICE_FB * CHUNK * 4 * sizeof(float);
        if (ws_size >= need_chunk) {
            hipMemsetAsync(d_out, 0, N_GRAPHS_C * sizeof(float), stream);
            chunk_kernel<<<nb * NSLICE_FB, 1024, 0, stream>>>(
                dij, q, g_ewald, row, col, (float*)d_ws, n_edges, nb, NSLICE_FB);
            finalize_kernel<<<(n_atoms + 255) / 256, 256, 0, stream>>>(
                (const float*)d_ws, batch, energy, force, n_atoms, NSLICE_FB);
        }
    }
}